// Round 8
// baseline (448.169 us; speedup 1.0000x reference)
//
#include <hip/hip_runtime.h>
#include <math.h>
#include <stdint.h>

typedef __attribute__((ext_vector_type(8))) short short8v;
typedef __attribute__((ext_vector_type(4))) float float4v;

// ---------------- utility ----------------
__device__ __forceinline__ float warp_sum64(float v) {
#pragma unroll
  for (int off = 32; off; off >>= 1) v += __shfl_xor(v, off);
  return v;
}

__device__ __forceinline__ float bf2f(unsigned short u) {
  return __uint_as_float((unsigned int)u << 16);
}
__device__ __forceinline__ unsigned short f2bf(float f) {   // RNE
  unsigned int u = __float_as_uint(f);
  unsigned int r = (u + 0x7FFFu + ((u >> 16) & 1u)) >> 16;
  return (unsigned short)r;
}

// ---------------- weight prep: fp32 W[K][Nw] -> hi/lo bf16 in MFMA-frag order ----
__global__ void wprep_kernel(const float* __restrict__ W, unsigned short* __restrict__ Wh,
                             unsigned short* __restrict__ Wl, int K, int Nw)
{
  int t = blockIdx.x * 256 + threadIdx.x;
  if (t >= K * Nw) return;
  int i = t & 7;
  int lane = (t >> 3) & 63;
  int frag = t >> 9;
  int ktiles = K >> 5;
  int n_tile = frag / ktiles, k_tile = frag - n_tile * ktiles;
  int k = k_tile * 32 + ((lane >> 4) << 3) + i;
  int n = (n_tile << 4) + (lane & 15);
  float v = W[(size_t)k * Nw + n];
  unsigned short hi = (unsigned short)(__float_as_uint(v) >> 16);   // trunc
  float rem = v - bf2f(hi);
  Wh[t] = hi;
  Wl[t] = f2bf(rem);
}

// ---------------- A-side split passes (conversion done ONCE, outside GEMM) ----
__global__ __launch_bounds__(256) void split_kernel(const float* __restrict__ in,
    unsigned short* __restrict__ hi, unsigned short* __restrict__ lo, size_t n4)
{
  size_t i0 = (size_t)blockIdx.x * 256 + threadIdx.x;
  size_t stride = (size_t)gridDim.x * 256;
  for (size_t idx = i0; idx < n4; idx += stride) {
    float4 v = ((const float4*)in)[idx];
    float vv[4] = {v.x, v.y, v.z, v.w};
    ushort4 h, l;
    unsigned short* hp = &h.x; unsigned short* lp = &l.x;
#pragma unroll
    for (int j = 0; j < 4; ++j) {
      unsigned short hh = (unsigned short)(__float_as_uint(vv[j]) >> 16);
      hp[j] = hh;
      lp[j] = f2bf(vv[j] - bf2f(hh));
    }
    ((ushort4*)hi)[idx] = h;
    ((ushort4*)lo)[idx] = l;
  }
}

// BN(scale,shift) + ELU + split: act [N][256] fp32 -> hi/lo bf16
__global__ __launch_bounds__(256) void bnsplit_kernel(const float* __restrict__ act,
    const float* __restrict__ scale, const float* __restrict__ shift,
    unsigned short* __restrict__ hi, unsigned short* __restrict__ lo, size_t n4)
{
  size_t i0 = (size_t)blockIdx.x * 256 + threadIdx.x;
  size_t stride = (size_t)gridDim.x * 256;
  for (size_t idx = i0; idx < n4; idx += stride) {
    float4 v = ((const float4*)act)[idx];
    int f = (int)((idx * 4) & 255);
    float4 sc = *(const float4*)(scale + f);
    float4 sh = *(const float4*)(shift + f);
    float vv[4];
    vv[0] = fmaf(v.x, sc.x, sh.x);
    vv[1] = fmaf(v.y, sc.y, sh.y);
    vv[2] = fmaf(v.z, sc.z, sh.z);
    vv[3] = fmaf(v.w, sc.w, sh.w);
    ushort4 h, l;
    unsigned short* hp = &h.x; unsigned short* lp = &l.x;
#pragma unroll
    for (int j = 0; j < 4; ++j) {
      float t = vv[j];
      t = t > 0.f ? t : expm1f(t);                 // ELU
      unsigned short hh = (unsigned short)(__float_as_uint(t) >> 16);
      hp[j] = hh;
      lp[j] = f2bf(t - bf2f(hh));
    }
    ((ushort4*)hi)[idx] = h;
    ((ushort4*)lo)[idx] = l;
  }
}

// ---------------- MFMA GEMM: C[M,Nw](bf16) = (Ah+Al)[M,K] @ (Bh+Bl) ----------------
// Register double-buffered K-pipeline; each wave computes 64x64.
// WM x WN wave grid (WM*WN == 4); BM = WM*64, BN = WN*64.
template<int WM, int WN>
__global__ __launch_bounds__(256) void gemm_mfma(
    const unsigned short* __restrict__ Ah, const unsigned short* __restrict__ Al,
    const unsigned short* __restrict__ Bh, const unsigned short* __restrict__ Bl,
    unsigned short* __restrict__ C, int M, int Nw, int K)
{
  constexpr int BM = WM * 64, BN = WN * 64;
  const int wid = threadIdx.x >> 6, lane = threadIdx.x & 63;
  const int wm = wid / WN, wn = wid % WN;
  const int m0 = blockIdx.x * BM + wm * 64;
  const int n0 = blockIdx.y * BN + wn * 64;
  const int ar = lane & 15;
  const int kb = (lane >> 4) << 3;
  const int ktiles = K >> 5;
  const int ntile0 = n0 >> 4;

  float4v acc[4][4];
#pragma unroll
  for (int mi = 0; mi < 4; ++mi)
#pragma unroll
    for (int ni = 0; ni < 4; ++ni)
      acc[mi][ni] = (float4v){0.f, 0.f, 0.f, 0.f};

  short8v bhA[4], blA[4], ahA[4], alA[4];
  short8v bhB[4], blB[4], ahB[4], alB[4];

#define LOADF(SUF, KT) do {                                                     \
    const int kt_ = (KT);                                                       \
    const int kk_ = kt_ * 32 + kb;                                              \
    _Pragma("unroll")                                                           \
    for (int ni = 0; ni < 4; ++ni) {                                            \
      size_t off = (((size_t)(ntile0 + ni) * ktiles + kt_) * 64 + lane) * 8;    \
      bh##SUF[ni] = *(const short8v*)(Bh + off);                                \
      bl##SUF[ni] = *(const short8v*)(Bl + off);                                \
    }                                                                           \
    _Pragma("unroll")                                                           \
    for (int mi = 0; mi < 4; ++mi) {                                            \
      int row = m0 + mi * 16 + ar;                                              \
      if (row < M) {                                                            \
        size_t off = (size_t)row * K + kk_;                                     \
        ah##SUF[mi] = *(const short8v*)(Ah + off);                              \
        al##SUF[mi] = *(const short8v*)(Al + off);                              \
      } else {                                                                  \
        ah##SUF[mi] = (short8v){0, 0, 0, 0, 0, 0, 0, 0};                        \
        al##SUF[mi] = (short8v){0, 0, 0, 0, 0, 0, 0, 0};                        \
      }                                                                         \
    }                                                                           \
  } while (0)

#define MFMAS(SUF) do {                                                         \
    _Pragma("unroll")                                                           \
    for (int mi = 0; mi < 4; ++mi)                                              \
      _Pragma("unroll")                                                         \
      for (int ni = 0; ni < 4; ++ni) {                                          \
        acc[mi][ni] = __builtin_amdgcn_mfma_f32_16x16x32_bf16(ah##SUF[mi], bh##SUF[ni], acc[mi][ni], 0, 0, 0); \
        acc[mi][ni] = __builtin_amdgcn_mfma_f32_16x16x32_bf16(ah##SUF[mi], bl##SUF[ni], acc[mi][ni], 0, 0, 0); \
        acc[mi][ni] = __builtin_amdgcn_mfma_f32_16x16x32_bf16(al##SUF[mi], bh##SUF[ni], acc[mi][ni], 0, 0, 0); \
      }                                                                         \
  } while (0)

  // software-pipelined K loop (ktiles is even: 4 or 8)
  LOADF(A, 0);
  int kt = 0;
  for (; kt < ktiles - 2; kt += 2) {
    LOADF(B, kt + 1);     // prefetch kt+1 before consuming kt
    MFMAS(A);
    LOADF(A, kt + 2);     // prefetch kt+2 before consuming kt+1
    MFMAS(B);
  }
  LOADF(B, kt + 1);
  MFMAS(A);
  MFMAS(B);

#undef LOADF
#undef MFMAS

  const int cc = lane & 15;
#pragma unroll
  for (int mi = 0; mi < 4; ++mi) {
    int rowb = m0 + mi * 16 + ((lane >> 4) << 2);
#pragma unroll
    for (int r = 0; r < 4; ++r) {
      int row = rowb + r;
      if (row < M) {
#pragma unroll
        for (int ni = 0; ni < 4; ++ni)
          C[(size_t)row * Nw + n0 + ni * 16 + cc] = f2bf(acc[mi][ni][r]);
      }
    }
  }
}

// ---------------- attention logits from bf16 h ----------------
template<int H>
__global__ void al_kernel(const unsigned short* __restrict__ h, const float* __restrict__ a_s,
                          const float* __restrict__ a_d, float* __restrict__ al_s,
                          float* __restrict__ al_d, int N)
{
  int n = blockIdx.x;
  int tid = threadIdx.x;
  int hh = tid >> 6, lane = tid & 63;
  float hv = bf2f(h[(size_t)n * (H * 64) + tid]);
  float ps = hv * a_s[tid];
  float pd = hv * a_d[tid];
  ps = warp_sum64(ps);
  pd = warp_sum64(pd);
  if (lane == 0) { al_s[n * H + hh] = ps; al_d[n * H + hh] = pd; }
}

// ---------------- per-position exp(leaky_relu), CSR order, no atomics ----------------
template<int H>
__global__ void edge_kernel(const int* __restrict__ csrSrc, const int* __restrict__ csrDst,
                            int Etot, const float* __restrict__ al_s,
                            const float* __restrict__ al_d, float* __restrict__ eeCsr)
{
  int t = blockIdx.x * 256 + threadIdx.x;
  if (t >= Etot * H) return;
  int pos = t / H, hh = t - pos * H;
  int s = csrSrc[pos], d = csrDst[pos];
  float x = al_s[s * H + hh] + al_d[d * H + hh];
  x = x > 0.f ? x : 0.2f * x;           // leaky_relu(0.2)
  eeCsr[t] = expf(x);                    // softmax shift-invariant: skip segment max
}

// ---------------- CSR build ----------------
__global__ void count_kernel(const int* __restrict__ dst, int E, int Etot, int* __restrict__ counts)
{
  int e = blockIdx.x * 256 + threadIdx.x;
  if (e >= Etot) return;
  int d = (e < E) ? dst[e] : (e - E);
  atomicAdd(&counts[d], 1);
}

__global__ void block_sum_kernel(const int* __restrict__ counts, int N, int* __restrict__ bsums)
{
  __shared__ int sd[256];
  int i = blockIdx.x * 256 + threadIdx.x;
  sd[threadIdx.x] = (i < N) ? counts[i] : 0;
  __syncthreads();
  for (int off = 128; off; off >>= 1) {
    if (threadIdx.x < off) sd[threadIdx.x] += sd[threadIdx.x + off];
    __syncthreads();
  }
  if (threadIdx.x == 0) bsums[blockIdx.x] = sd[0];
}

// one-block parallel exclusive scan over bsums (nb <= 256)
__global__ void scan_bsums_kernel(int* bsums, int nb)
{
  __shared__ int sd[256];
  int t = threadIdx.x;
  int v = (t < nb) ? bsums[t] : 0;
  sd[t] = v;
  __syncthreads();
  for (int off = 1; off < 256; off <<= 1) {
    int x = (t >= off) ? sd[t - off] : 0;
    __syncthreads();
    sd[t] += x;
    __syncthreads();
  }
  if (t < nb) bsums[t] = sd[t] - v;  // exclusive
}

__global__ void scan_write_kernel(const int* __restrict__ counts, int N,
                                  const int* __restrict__ bsums, int* __restrict__ rowStart, int Etot)
{
  __shared__ int sd[256];
  int i = blockIdx.x * 256 + threadIdx.x;
  int v = (i < N) ? counts[i] : 0;
  sd[threadIdx.x] = v;
  __syncthreads();
  for (int off = 1; off < 256; off <<= 1) {
    int x = (threadIdx.x >= off) ? sd[threadIdx.x - off] : 0;
    __syncthreads();
    sd[threadIdx.x] += x;
    __syncthreads();
  }
  if (i < N) rowStart[i] = bsums[blockIdx.x] + sd[threadIdx.x] - v;  // exclusive
  if (i == N - 1) rowStart[N] = Etot;
}

__global__ void fill_kernel(const int* __restrict__ src, const int* __restrict__ dst,
                            int E, int Etot, const int* __restrict__ rowStart,
                            int* __restrict__ cursor, int* __restrict__ csrSrc,
                            int* __restrict__ csrDst)
{
  int e = blockIdx.x * 256 + threadIdx.x;
  if (e >= Etot) return;
  int s, d;
  if (e < E) { s = src[e]; d = dst[e]; } else { s = d = e - E; }
  int pos = rowStart[d] + atomicAdd(&cursor[d], 1);
  csrSrc[pos] = s;
  csrDst[pos] = d;
}

// ---------------- aggregation: wave per node, bf16 gather, inline denom, 4x ILP ----
template<int HC_>
__global__ __launch_bounds__(256) void aggregate_kernel(
    const unsigned short* __restrict__ h16, const float* __restrict__ eeCsr,
    const int* __restrict__ csrSrc, const int* __restrict__ rowStart,
    float* __restrict__ outp, int N, const float* __restrict__ bias, int doElu)
{
  constexpr int H_ = HC_ / 64;       // heads (4 or 1)
  constexpr int FPL = HC_ / 64;      // features per lane (4 or 1)
  int wid = (int)(blockIdx.x * (blockDim.x >> 6) + (threadIdx.x >> 6));
  if (wid >= N) return;
  const int lane = threadIdx.x & 63;
  const int head = (H_ == 4) ? (lane >> 4) : 0;
  const int start = rowStart[wid], end = rowStart[wid + 1];

  float acc[FPL] = {};
  float wsum = 0.f;

  for (int base = start; base < end; base += 64) {
    int cnt = end - base; if (cnt > 64) cnt = 64;
    int s_l = (lane < cnt) ? csrSrc[base + lane] : 0;
    int i = 0;
    for (; i + 4 <= cnt; i += 4) {
      int s0 = __shfl(s_l, i);
      int s1 = __shfl(s_l, i + 1);
      int s2 = __shfl(s_l, i + 2);
      int s3 = __shfl(s_l, i + 3);
      float w0 = eeCsr[(size_t)(base + i) * H_ + head];
      float w1 = eeCsr[(size_t)(base + i + 1) * H_ + head];
      float w2 = eeCsr[(size_t)(base + i + 2) * H_ + head];
      float w3 = eeCsr[(size_t)(base + i + 3) * H_ + head];
      if (FPL == 4) {
        ushort4 r0 = ((const ushort4*)(h16 + (size_t)s0 * HC_))[lane];
        ushort4 r1 = ((const ushort4*)(h16 + (size_t)s1 * HC_))[lane];
        ushort4 r2 = ((const ushort4*)(h16 + (size_t)s2 * HC_))[lane];
        ushort4 r3 = ((const ushort4*)(h16 + (size_t)s3 * HC_))[lane];
        wsum += (w0 + w1) + (w2 + w3);
        acc[0] = fmaf(w0, bf2f(r0.x), acc[0]);
        acc[1] = fmaf(w0, bf2f(r0.y), acc[1]);
        acc[2] = fmaf(w0, bf2f(r0.z), acc[2]);
        acc[3] = fmaf(w0, bf2f(r0.w), acc[3]);
        acc[0] = fmaf(w1, bf2f(r1.x), acc[0]);
        acc[1] = fmaf(w1, bf2f(r1.y), acc[1]);
        acc[2] = fmaf(w1, bf2f(r1.z), acc[2]);
        acc[3] = fmaf(w1, bf2f(r1.w), acc[3]);
        acc[0] = fmaf(w2, bf2f(r2.x), acc[0]);
        acc[1] = fmaf(w2, bf2f(r2.y), acc[1]);
        acc[2] = fmaf(w2, bf2f(r2.z), acc[2]);
        acc[3] = fmaf(w2, bf2f(r2.w), acc[3]);
        acc[0] = fmaf(w3, bf2f(r3.x), acc[0]);
        acc[1] = fmaf(w3, bf2f(r3.y), acc[1]);
        acc[2] = fmaf(w3, bf2f(r3.z), acc[2]);
        acc[3] = fmaf(w3, bf2f(r3.w), acc[3]);
      } else {
        unsigned short r0 = h16[(size_t)s0 * HC_ + lane];
        unsigned short r1 = h16[(size_t)s1 * HC_ + lane];
        unsigned short r2 = h16[(size_t)s2 * HC_ + lane];
        unsigned short r3 = h16[(size_t)s3 * HC_ + lane];
        wsum += (w0 + w1) + (w2 + w3);
        acc[0] = fmaf(w0, bf2f(r0), acc[0]);
        acc[0] = fmaf(w1, bf2f(r1), acc[0]);
        acc[0] = fmaf(w2, bf2f(r2), acc[0]);
        acc[0] = fmaf(w3, bf2f(r3), acc[0]);
      }
    }
    for (; i < cnt; ++i) {
      int s0 = __shfl(s_l, i);
      float w0 = eeCsr[(size_t)(base + i) * H_ + head];
      wsum += w0;
      if (FPL == 4) {
        ushort4 r0 = ((const ushort4*)(h16 + (size_t)s0 * HC_))[lane];
        acc[0] = fmaf(w0, bf2f(r0.x), acc[0]);
        acc[1] = fmaf(w0, bf2f(r0.y), acc[1]);
        acc[2] = fmaf(w0, bf2f(r0.z), acc[2]);
        acc[3] = fmaf(w0, bf2f(r0.w), acc[3]);
      } else {
        unsigned short r0 = h16[(size_t)s0 * HC_ + lane];
        acc[0] = fmaf(w0, bf2f(r0), acc[0]);
      }
    }
  }

  float inv = 1.0f / wsum;
  if (FPL == 4) {
    float4 o;
    o.x = acc[0] * inv; o.y = acc[1] * inv; o.z = acc[2] * inv; o.w = acc[3] * inv;
    if (bias) {
      const float4 b = ((const float4*)bias)[lane];
      o.x += b.x; o.y += b.y; o.z += b.z; o.w += b.w;
    }
    if (doElu) {
      o.x = o.x > 0.f ? o.x : expm1f(o.x);
      o.y = o.y > 0.f ? o.y : expm1f(o.y);
      o.z = o.z > 0.f ? o.z : expm1f(o.z);
      o.w = o.w > 0.f ? o.w : expm1f(o.w);
    }
    ((float4*)(outp + (size_t)wid * HC_))[lane] = o;
  } else {
    float o = acc[0] * inv;
    if (bias) o += bias[lane];
    if (doElu) o = o > 0.f ? o : expm1f(o);
    outp[(size_t)wid * HC_ + lane] = o;
  }
}

// ---------------- batch norm stats: wave-per-row-group, float4, LDS reduce ----------------
__global__ __launch_bounds__(256) void bn_stats_kernel(const float* __restrict__ x, int N,
                                float* __restrict__ sums, float* __restrict__ sumsq)
{
  const int wid = threadIdx.x >> 6, lane = threadIdx.x & 63;
  const int gw = blockIdx.x * 4 + wid;         // global wave id
  const int tw = gridDim.x * 4;                // total waves
  float4 s = make_float4(0.f, 0.f, 0.f, 0.f);
  float4 q = make_float4(0.f, 0.f, 0.f, 0.f);
#pragma unroll 4
  for (int r = gw; r < N; r += tw) {
    float4 v = ((const float4*)(x + (size_t)r * 256))[lane];
    s.x += v.x; s.y += v.y; s.z += v.z; s.w += v.w;
    q.x = fmaf(v.x, v.x, q.x); q.y = fmaf(v.y, v.y, q.y);
    q.z = fmaf(v.z, v.z, q.z); q.w = fmaf(v.w, v.w, q.w);
  }
  __shared__ float ls[4][512];
  *(float4*)&ls[wid][lane * 4] = s;
  *(float4*)&ls[wid][256 + lane * 4] = q;
  __syncthreads();
  const int t = threadIdx.x;
  float a = ls[0][t] + ls[1][t] + ls[2][t] + ls[3][t];
  float b = ls[0][t + 256] + ls[1][t + 256] + ls[2][t + 256] + ls[3][t + 256];
  atomicAdd(&sums[t], a);
  atomicAdd(&sumsq[t], b);
}

__global__ void bn_final_kernel(const float* __restrict__ sums, const float* __restrict__ sumsq,
                                const float* __restrict__ g, const float* __restrict__ be,
                                int N, float* __restrict__ scale, float* __restrict__ shift)
{
  int f = threadIdx.x;
  float mu = sums[f] / N;
  float var = sumsq[f] / N - mu * mu;
  float rs = rsqrtf(var + 1e-5f);
  float sc = g[f] * rs;
  scale[f] = sc;
  shift[f] = be[f] - mu * sc;
}

// ---------------- MLP head: thread-per-node, LDS weight broadcast ----------------
__global__ __launch_bounds__(256) void mlp_kernel(const float* __restrict__ h,
                           const float* __restrict__ fw1,
                           const float* __restrict__ fb1, const float* __restrict__ fw2,
                           const float* __restrict__ fb2, float* __restrict__ out, int N)
{
  __shared__ float w1s[64][32];   // fw1 [k][j]
  __shared__ float w2s[32][2];
  __shared__ float b1s[32];
  const int t = threadIdx.x;
  for (int i = t; i < 64 * 32; i += 256) w1s[i >> 5][i & 31] = fw1[i];
  if (t < 64) w2s[t >> 1][t & 1] = fw2[t];
  if (t < 32) b1s[t] = fb1[t];
  __syncthreads();

  int n = blockIdx.x * 256 + t;   // one node per thread
  if (n >= N) return;

  float hv[64];
#pragma unroll
  for (int k4 = 0; k4 < 16; ++k4) {
    float4 v = *(const float4*)(h + (size_t)n * 64 + k4 * 4);
    hv[k4 * 4 + 0] = v.x; hv[k4 * 4 + 1] = v.y;
    hv[k4 * 4 + 2] = v.z; hv[k4 * 4 + 3] = v.w;
  }
  float hid[32];
#pragma unroll
  for (int j = 0; j < 32; ++j) hid[j] = b1s[j];
#pragma unroll
  for (int k = 0; k < 64; ++k) {
    float hk = hv[k];
#pragma unroll
    for (int jb = 0; jb < 8; ++jb) {
      float4 wv = *(const float4*)&w1s[k][jb * 4];
      hid[jb * 4 + 0] = fmaf(hk, wv.x, hid[jb * 4 + 0]);
      hid[jb * 4 + 1] = fmaf(hk, wv.y, hid[jb * 4 + 1]);
      hid[jb * 4 + 2] = fmaf(hk, wv.z, hid[jb * 4 + 2]);
      hid[jb * 4 + 3] = fmaf(hk, wv.w, hid[jb * 4 + 3]);
    }
  }
  float p0 = fb2[0], p1 = fb2[1];
#pragma unroll
  for (int j = 0; j < 32; ++j) {
    float r = fmaxf(hid[j], 0.f);
    p0 = fmaf(r, w2s[j][0], p0);
    p1 = fmaf(r, w2s[j][1], p1);
  }
  *(float2*)(out + (size_t)n * 2) = make_float2(p0, p1);
}

// ---------------- host ----------------
extern "C" void kernel_launch(void* const* d_in, const int* in_sizes, int n_in,
                              void* d_out, int out_size, void* d_ws, size_t ws_size,
                              hipStream_t stream)
{
  const float* x   = (const float*)d_in[0];
  const int*   ei  = (const int*)d_in[1];
  const float* W1  = (const float*)d_in[2];
  const float* a1s = (const float*)d_in[3];
  const float* a1d = (const float*)d_in[4];
  const float* W2  = (const float*)d_in[6];
  const float* a2s = (const float*)d_in[7];
  const float* a2d = (const float*)d_in[8];
  const float* W3  = (const float*)d_in[10];
  const float* a3s = (const float*)d_in[11];
  const float* a3d = (const float*)d_in[12];
  const float* b3  = (const float*)d_in[13];
  const float* g1  = (const float*)d_in[14];
  const float* be1 = (const float*)d_in[15];
  const float* g2  = (const float*)d_in[16];
  const float* be2 = (const float*)d_in[17];
  const float* fw1 = (const float*)d_in[18];
  const float* fb1 = (const float*)d_in[19];
  const float* fw2 = (const float*)d_in[20];
  const float* fb2 = (const float*)d_in[21];
  float* out = (float*)d_out;

  const int F = 128;
  const int N = in_sizes[0] / F;
  const int E = in_sizes[1] / 2;
  const int Etot = E + N;
  const int* srcIdx = ei;
  const int* dstIdx = ei + E;

  // workspace layout (256B aligned slices)
  char* w = (char*)d_ws;
  auto alloc = [&](size_t bytes) -> void* {
    void* p = (void*)w;
    w += (bytes + 255) & ~(size_t)255;
    return p;
  };
  unsigned short* h16 = (unsigned short*)alloc((size_t)N * 256 * 2);
  float* act     = (float*)alloc((size_t)N * 256 * 4);
  unsigned short* aHi = (unsigned short*)alloc((size_t)N * 256 * 2);
  unsigned short* aLo = (unsigned short*)alloc((size_t)N * 256 * 2);
  float* eeCsr   = (float*)alloc((size_t)Etot * 4 * 4);
  float* als     = (float*)alloc((size_t)N * 4 * 4);
  float* ald     = (float*)alloc((size_t)N * 4 * 4);
  int*   counts  = (int*)alloc((size_t)N * 4);
  int*   cursor  = (int*)alloc((size_t)N * 4);
  int*   rowStart= (int*)alloc((size_t)(N + 1) * 4);
  int*   csrSrc  = (int*)alloc((size_t)Etot * 4);
  int*   csrDst  = (int*)alloc((size_t)Etot * 4);
  int*   bsums   = (int*)alloc((size_t)((N + 255) / 256) * 4);
  float* sums    = (float*)alloc(256 * 4);
  float* sumsq   = (float*)alloc(256 * 4);
  float* scale1  = (float*)alloc(256 * 4);
  float* shift1  = (float*)alloc(256 * 4);
  float* scale2  = (float*)alloc(256 * 4);
  float* shift2  = (float*)alloc(256 * 4);
  unsigned short* w1h = (unsigned short*)alloc((size_t)128 * 256 * 2);
  unsigned short* w1l = (unsigned short*)alloc((size_t)128 * 256 * 2);
  unsigned short* w2h = (unsigned short*)alloc((size_t)256 * 256 * 2);
  unsigned short* w2l = (unsigned short*)alloc((size_t)256 * 256 * 2);
  unsigned short* w3h = (unsigned short*)alloc((size_t)256 * 64 * 2);
  unsigned short* w3l = (unsigned short*)alloc((size_t)256 * 64 * 2);

  const int nb = (N + 255) / 256;
  const int ebk = (Etot + 255) / 256;
  const int aggBlocks = (N + 3) / 4;

  // ---- weight prep (frag-ordered bf16 hi/lo) ----
  wprep_kernel<<<(128 * 256 + 255) / 256, 256, 0, stream>>>(W1, w1h, w1l, 128, 256);
  wprep_kernel<<<(256 * 256 + 255) / 256, 256, 0, stream>>>(W2, w2h, w2l, 256, 256);
  wprep_kernel<<<(256 * 64 + 255) / 256, 256, 0, stream>>>(W3, w3h, w3l, 256, 64);

  // ---- CSR build (reused by all 3 layers) ----
  hipMemsetAsync(counts, 0, (size_t)N * 4, stream);
  hipMemsetAsync(cursor, 0, (size_t)N * 4, stream);
  count_kernel<<<ebk, 256, 0, stream>>>(dstIdx, E, Etot, counts);
  block_sum_kernel<<<nb, 256, 0, stream>>>(counts, N, bsums);
  scan_bsums_kernel<<<1, 256, 0, stream>>>(bsums, nb);
  scan_write_kernel<<<nb, 256, 0, stream>>>(counts, N, bsums, rowStart, Etot);
  fill_kernel<<<ebk, 256, 0, stream>>>(srcIdx, dstIdx, E, Etot, rowStart, cursor, csrSrc, csrDst);

  dim3 g12((N + 63) / 64, 1);     // layers 1,2: BM=64, BN=256 (WM=1, WN=4) — A read once
  dim3 g3((N + 255) / 256, 1);    // layer 3: BM=256, BN=64 (WM=4, WN=1)

  // ---- GAT layer 1: x[N,128] -> act[N,256] (bias cancels in BN) ----
  split_kernel<<<2048, 256, 0, stream>>>(x, aHi, aLo, (size_t)N * 128 / 4);  // aHi/aLo as [N][128]
  gemm_mfma<1, 4><<<g12, 256, 0, stream>>>(aHi, aLo, w1h, w1l, h16, N, 256, 128);
  al_kernel<4><<<N, 256, 0, stream>>>(h16, a1s, a1d, als, ald, N);
  edge_kernel<4><<<(Etot * 4 + 255) / 256, 256, 0, stream>>>(csrSrc, csrDst, Etot, als, ald, eeCsr);
  aggregate_kernel<256><<<aggBlocks, 256, 0, stream>>>(h16, eeCsr, csrSrc, rowStart, act, N, nullptr, 0);
  // BN1 stats -> scale1/shift1
  hipMemsetAsync(sums, 0, 256 * 4, stream);
  hipMemsetAsync(sumsq, 0, 256 * 4, stream);
  bn_stats_kernel<<<512, 256, 0, stream>>>(act, N, sums, sumsq);
  bn_final_kernel<<<1, 256, 0, stream>>>(sums, sumsq, g1, be1, N, scale1, shift1);

  // ---- GAT layer 2: elu(bn(act)) @ W2 -> h16 ----
  bnsplit_kernel<<<2048, 256, 0, stream>>>(act, scale1, shift1, aHi, aLo, (size_t)N * 256 / 4);
  gemm_mfma<1, 4><<<g12, 256, 0, stream>>>(aHi, aLo, w2h, w2l, h16, N, 256, 256);
  al_kernel<4><<<N, 256, 0, stream>>>(h16, a2s, a2d, als, ald, N);
  edge_kernel<4><<<(Etot * 4 + 255) / 256, 256, 0, stream>>>(csrSrc, csrDst, Etot, als, ald, eeCsr);
  aggregate_kernel<256><<<aggBlocks, 256, 0, stream>>>(h16, eeCsr, csrSrc, rowStart, act, N, nullptr, 0);
  // BN2 stats -> scale2/shift2
  hipMemsetAsync(sums, 0, 256 * 4, stream);
  hipMemsetAsync(sumsq, 0, 256 * 4, stream);
  bn_stats_kernel<<<512, 256, 0, stream>>>(act, N, sums, sumsq);
  bn_final_kernel<<<1, 256, 0, stream>>>(sums, sumsq, g2, be2, N, scale2, shift2);

  // ---- GAT layer 3 (1 head, C=64): elu(bn(act)) @ W3 -> h16[N,64]; agg +b3, ELU ----
  bnsplit_kernel<<<2048, 256, 0, stream>>>(act, scale2, shift2, aHi, aLo, (size_t)N * 256 / 4);
  gemm_mfma<4, 1><<<g3, 256, 0, stream>>>(aHi, aLo, w3h, w3l, h16, N, 64, 256);
  al_kernel<1><<<N, 64, 0, stream>>>(h16, a3s, a3d, als, ald, N);
  edge_kernel<1><<<(Etot + 255) / 256, 256, 0, stream>>>(csrSrc, csrDst, Etot, als, ald, eeCsr);
  aggregate_kernel<64><<<aggBlocks, 256, 0, stream>>>(h16, eeCsr, csrSrc, rowStart, act, N, b3, 1);

  // ---- MLP head ----
  mlp_kernel<<<(N + 255) / 256, 256, 0, stream>>>(act, fw1, fb1, fw2, fb2, out, N);
}

// Round 9
// 375.844 us; speedup vs baseline: 1.1924x; 1.1924x over previous
//
#include <hip/hip_runtime.h>
#include <math.h>
#include <stdint.h>

typedef __attribute__((ext_vector_type(8))) short short8v;
typedef __attribute__((ext_vector_type(4))) float float4v;

__device__ __forceinline__ float bf2f(unsigned short u) {
  return __uint_as_float((unsigned int)u << 16);
}
__device__ __forceinline__ unsigned short f2bf(float f) {   // RNE
  unsigned int u = __float_as_uint(f);
  unsigned int r = (u + 0x7FFFu + ((u >> 16) & 1u)) >> 16;
  return (unsigned short)r;
}
__device__ __forceinline__ float exp_lrelu(float x) {
  x = x > 0.f ? x : 0.2f * x;
  return expf(x);       // softmax shift-invariant: segment-max skipped
}

// ---------------- weight prep: fp32 W[K][Nw] -> hi/lo bf16 in MFMA-frag order ----
__global__ void wprep_kernel(const float* __restrict__ W, unsigned short* __restrict__ Wh,
                             unsigned short* __restrict__ Wl, int K, int Nw)
{
  int t = blockIdx.x * 256 + threadIdx.x;
  if (t >= K * Nw) return;
  int i = t & 7;
  int lane = (t >> 3) & 63;
  int frag = t >> 9;
  int ktiles = K >> 5;
  int n_tile = frag / ktiles, k_tile = frag - n_tile * ktiles;
  int k = k_tile * 32 + ((lane >> 4) << 3) + i;
  int n = (n_tile << 4) + (lane & 15);
  float v = W[(size_t)k * Nw + n];
  unsigned short hi = (unsigned short)(__float_as_uint(v) >> 16);   // trunc
  float rem = v - bf2f(hi);
  Wh[t] = hi;
  Wl[t] = f2bf(rem);
}

// ---------------- A-side split passes ----------------
__global__ __launch_bounds__(256) void split_kernel(const float* __restrict__ in,
    unsigned short* __restrict__ hi, unsigned short* __restrict__ lo, size_t n4)
{
  size_t i0 = (size_t)blockIdx.x * 256 + threadIdx.x;
  size_t stride = (size_t)gridDim.x * 256;
  for (size_t idx = i0; idx < n4; idx += stride) {
    float4 v = ((const float4*)in)[idx];
    float vv[4] = {v.x, v.y, v.z, v.w};
    ushort4 h, l;
    unsigned short* hp = &h.x; unsigned short* lp = &l.x;
#pragma unroll
    for (int j = 0; j < 4; ++j) {
      unsigned short hh = (unsigned short)(__float_as_uint(vv[j]) >> 16);
      hp[j] = hh;
      lp[j] = f2bf(vv[j] - bf2f(hh));
    }
    ((ushort4*)hi)[idx] = h;
    ((ushort4*)lo)[idx] = l;
  }
}

__global__ __launch_bounds__(256) void bnsplit_kernel(const float* __restrict__ act,
    const float* __restrict__ scale, const float* __restrict__ shift,
    unsigned short* __restrict__ hi, unsigned short* __restrict__ lo, size_t n4)
{
  size_t i0 = (size_t)blockIdx.x * 256 + threadIdx.x;
  size_t stride = (size_t)gridDim.x * 256;
  for (size_t idx = i0; idx < n4; idx += stride) {
    float4 v = ((const float4*)act)[idx];
    int f = (int)((idx * 4) & 255);
    float4 sc = *(const float4*)(scale + f);
    float4 sh = *(const float4*)(shift + f);
    float vv[4];
    vv[0] = fmaf(v.x, sc.x, sh.x);
    vv[1] = fmaf(v.y, sc.y, sh.y);
    vv[2] = fmaf(v.z, sc.z, sh.z);
    vv[3] = fmaf(v.w, sc.w, sh.w);
    ushort4 h, l;
    unsigned short* hp = &h.x; unsigned short* lp = &l.x;
#pragma unroll
    for (int j = 0; j < 4; ++j) {
      float t = vv[j];
      t = t > 0.f ? t : expm1f(t);                 // ELU
      unsigned short hh = (unsigned short)(__float_as_uint(t) >> 16);
      hp[j] = hh;
      lp[j] = f2bf(t - bf2f(hh));
    }
    ((ushort4*)hi)[idx] = h;
    ((ushort4*)lo)[idx] = l;
  }
}

// ---------------- MFMA GEMM + fused attention-logit epilogue ----------------
// C[M,Nw](bf16) = (Ah+Al)[M,K] @ (Bh+Bl); al_s/al_d[row][head] = dot(h_row_head, a_*)
// Wave grid WM x WN (WM*WN==4). HEADS==WN (4) for 256-col layers, 1 for layer 3.
template<int WM, int WN, int KTILES, int HEADS>
__global__ __launch_bounds__(256) void gemm_al(
    const unsigned short* __restrict__ Ah, const unsigned short* __restrict__ Al,
    const unsigned short* __restrict__ Bh, const unsigned short* __restrict__ Bl,
    const float* __restrict__ a_s, const float* __restrict__ a_d,
    unsigned short* __restrict__ C, float* __restrict__ al_s, float* __restrict__ al_d,
    int M)
{
  constexpr int BM = WM * 64, Nw = WN * 64, K = KTILES * 32;
  const int wid = threadIdx.x >> 6, lane = threadIdx.x & 63;
  const int wm = wid / WN, wn = wid % WN;
  const int m0 = blockIdx.x * BM + wm * 64;
  const int n0 = wn * 64;
  const int ar = lane & 15;
  const int kb = (lane >> 4) << 3;
  const int ntile0 = n0 >> 4;

  float4v acc[4][4];
#pragma unroll
  for (int mi = 0; mi < 4; ++mi)
#pragma unroll
    for (int ni = 0; ni < 4; ++ni)
      acc[mi][ni] = (float4v){0.f, 0.f, 0.f, 0.f};

  for (int kt = 0; kt < KTILES; ++kt) {
    const int kk = kt * 32 + kb;
    short8v bh[4], bl[4];
#pragma unroll
    for (int ni = 0; ni < 4; ++ni) {
      size_t off = (((size_t)(ntile0 + ni) * KTILES + kt) * 64 + lane) * 8;
      bh[ni] = *(const short8v*)(Bh + off);
      bl[ni] = *(const short8v*)(Bl + off);
    }
    short8v ah[4], al_[4];
#pragma unroll
    for (int mi = 0; mi < 4; ++mi) {
      int row = m0 + mi * 16 + ar;
      if (row < M) {
        size_t off = (size_t)row * K + kk;
        ah[mi] = *(const short8v*)(Ah + off);
        al_[mi] = *(const short8v*)(Al + off);
      } else {
        ah[mi] = (short8v){0, 0, 0, 0, 0, 0, 0, 0};
        al_[mi] = (short8v){0, 0, 0, 0, 0, 0, 0, 0};
      }
    }
#pragma unroll
    for (int mi = 0; mi < 4; ++mi)
#pragma unroll
      for (int ni = 0; ni < 4; ++ni) {
        acc[mi][ni] = __builtin_amdgcn_mfma_f32_16x16x32_bf16(ah[mi], bh[ni], acc[mi][ni], 0, 0, 0);
        acc[mi][ni] = __builtin_amdgcn_mfma_f32_16x16x32_bf16(ah[mi], bl[ni], acc[mi][ni], 0, 0, 0);
        acc[mi][ni] = __builtin_amdgcn_mfma_f32_16x16x32_bf16(al_[mi], bh[ni], acc[mi][ni], 0, 0, 0);
      }
  }

  const int cc = lane & 15;
  // C write (values rounded to bf16 exactly as consumed downstream)
#pragma unroll
  for (int mi = 0; mi < 4; ++mi) {
    int rowb = m0 + mi * 16 + ((lane >> 4) << 2);
#pragma unroll
    for (int r = 0; r < 4; ++r) {
      int row = rowb + r;
      if (row < M) {
#pragma unroll
        for (int ni = 0; ni < 4; ++ni)
          C[(size_t)row * Nw + n0 + ni * 16 + cc] = f2bf(acc[mi][ni][r]);
      }
    }
  }

  // fused attention-logit epilogue (use bf16-rounded value = exact match of old al_kernel)
  const int head = (HEADS == 4) ? wn : 0;
  float as_[4], ad_[4];
#pragma unroll
  for (int ni = 0; ni < 4; ++ni) {
    as_[ni] = a_s[head * 64 + ni * 16 + cc];
    ad_[ni] = a_d[head * 64 + ni * 16 + cc];
  }
#pragma unroll
  for (int mi = 0; mi < 4; ++mi) {
#pragma unroll
    for (int r = 0; r < 4; ++r) {
      float h0 = bf2f(f2bf(acc[mi][0][r]));
      float h1 = bf2f(f2bf(acc[mi][1][r]));
      float h2 = bf2f(f2bf(acc[mi][2][r]));
      float h3 = bf2f(f2bf(acc[mi][3][r]));
      float ps = h0 * as_[0] + h1 * as_[1] + h2 * as_[2] + h3 * as_[3];
      float pd = h0 * ad_[0] + h1 * ad_[1] + h2 * ad_[2] + h3 * ad_[3];
#pragma unroll
      for (int off = 1; off < 16; off <<= 1) {
        ps += __shfl_xor(ps, off);
        pd += __shfl_xor(pd, off);
      }
      int row = m0 + mi * 16 + ((lane >> 4) << 2) + r;
      if (cc == 0 && row < M) {
        al_s[row * HEADS + head] = ps;
        al_d[row * HEADS + head] = pd;
      }
    }
  }
}

// ---------------- CSR build ----------------
__global__ void count_kernel(const int* __restrict__ dst, int E, int Etot, int* __restrict__ counts)
{
  int e = blockIdx.x * 256 + threadIdx.x;
  if (e >= Etot) return;
  int d = (e < E) ? dst[e] : (e - E);
  atomicAdd(&counts[d], 1);
}

__global__ void block_sum_kernel(const int* __restrict__ counts, int N, int* __restrict__ bsums)
{
  __shared__ int sd[256];
  int i = blockIdx.x * 256 + threadIdx.x;
  sd[threadIdx.x] = (i < N) ? counts[i] : 0;
  __syncthreads();
  for (int off = 128; off; off >>= 1) {
    if (threadIdx.x < off) sd[threadIdx.x] += sd[threadIdx.x + off];
    __syncthreads();
  }
  if (threadIdx.x == 0) bsums[blockIdx.x] = sd[0];
}

__global__ void scan_bsums_kernel(int* bsums, int nb)
{
  __shared__ int sd[256];
  int t = threadIdx.x;
  int v = (t < nb) ? bsums[t] : 0;
  sd[t] = v;
  __syncthreads();
  for (int off = 1; off < 256; off <<= 1) {
    int x = (t >= off) ? sd[t - off] : 0;
    __syncthreads();
    sd[t] += x;
    __syncthreads();
  }
  if (t < nb) bsums[t] = sd[t] - v;  // exclusive
}

__global__ void scan_write_kernel(const int* __restrict__ counts, int N,
                                  const int* __restrict__ bsums, int* __restrict__ rowStart, int Etot)
{
  __shared__ int sd[256];
  int i = blockIdx.x * 256 + threadIdx.x;
  int v = (i < N) ? counts[i] : 0;
  sd[threadIdx.x] = v;
  __syncthreads();
  for (int off = 1; off < 256; off <<= 1) {
    int x = (threadIdx.x >= off) ? sd[threadIdx.x - off] : 0;
    __syncthreads();
    sd[threadIdx.x] += x;
    __syncthreads();
  }
  if (i < N) rowStart[i] = bsums[blockIdx.x] + sd[threadIdx.x] - v;  // exclusive
  if (i == N - 1) rowStart[N] = Etot;
}

__global__ void fill_kernel(const int* __restrict__ src, const int* __restrict__ dst,
                            int E, int Etot, const int* __restrict__ rowStart,
                            int* __restrict__ cursor, int* __restrict__ csrSrc)
{
  int e = blockIdx.x * 256 + threadIdx.x;
  if (e >= Etot) return;
  int s, d;
  if (e < E) { s = src[e]; d = dst[e]; } else { s = d = e - E; }
  int pos = rowStart[d] + atomicAdd(&cursor[d], 1);
  csrSrc[pos] = s;
}

// ---------------- fused aggregation: edge weights computed inline ----------------
// w[e][h] = exp(leaky_relu(al_s[src][h] + al_d[dst][h])); out = sum(w*h[src]) / sum(w)
template<int HC_>
__global__ __launch_bounds__(256) void aggregate_fused(
    const unsigned short* __restrict__ h16,
    const float* __restrict__ als, const float* __restrict__ ald,
    const int* __restrict__ csrSrc, const int* __restrict__ rowStart,
    float* __restrict__ outp, int N, const float* __restrict__ bias, int doElu)
{
  constexpr int H_ = HC_ / 64;       // heads (4 or 1)
  constexpr int FPL = HC_ / 64;      // features per lane
  __shared__ float ldsW[4][64 * H_];
  const int wl = threadIdx.x >> 6;
  int wid = blockIdx.x * 4 + wl;
  if (wid >= N) return;
  const int lane = threadIdx.x & 63;
  const int head = (H_ == 4) ? (lane >> 4) : 0;
  const int start = rowStart[wid], end = rowStart[wid + 1];

  float ad0, ad1, ad2, ad3;
  if (H_ == 4) {
    float4 adv = ((const float4*)ald)[wid];
    ad0 = adv.x; ad1 = adv.y; ad2 = adv.z; ad3 = adv.w;
  } else {
    ad0 = ald[wid]; ad1 = ad2 = ad3 = 0.f;
  }

  float acc[FPL] = {};
  float wsum = 0.f;

  for (int base = start; base < end; base += 64) {
    int cnt = end - base; if (cnt > 64) cnt = 64;
    int s_l = 0;
    if (lane < cnt) {
      s_l = csrSrc[base + lane];
      if (H_ == 4) {
        float4 av = ((const float4*)als)[s_l];
        float4 w4;
        w4.x = exp_lrelu(av.x + ad0);
        w4.y = exp_lrelu(av.y + ad1);
        w4.z = exp_lrelu(av.z + ad2);
        w4.w = exp_lrelu(av.w + ad3);
        *(float4*)&ldsW[wl][lane * 4] = w4;
      } else {
        ldsW[wl][lane] = exp_lrelu(als[s_l] + ad0);
      }
    }
    int i = 0;
    for (; i + 4 <= cnt; i += 4) {
      int s0 = __shfl(s_l, i);
      int s1 = __shfl(s_l, i + 1);
      int s2 = __shfl(s_l, i + 2);
      int s3 = __shfl(s_l, i + 3);
      float w0 = ldsW[wl][(i + 0) * H_ + head];
      float w1 = ldsW[wl][(i + 1) * H_ + head];
      float w2 = ldsW[wl][(i + 2) * H_ + head];
      float w3 = ldsW[wl][(i + 3) * H_ + head];
      if (FPL == 4) {
        ushort4 r0 = ((const ushort4*)(h16 + (size_t)s0 * HC_))[lane];
        ushort4 r1 = ((const ushort4*)(h16 + (size_t)s1 * HC_))[lane];
        ushort4 r2 = ((const ushort4*)(h16 + (size_t)s2 * HC_))[lane];
        ushort4 r3 = ((const ushort4*)(h16 + (size_t)s3 * HC_))[lane];
        wsum += (w0 + w1) + (w2 + w3);
        acc[0] = fmaf(w0, bf2f(r0.x), acc[0]);
        acc[1] = fmaf(w0, bf2f(r0.y), acc[1]);
        acc[2] = fmaf(w0, bf2f(r0.z), acc[2]);
        acc[3] = fmaf(w0, bf2f(r0.w), acc[3]);
        acc[0] = fmaf(w1, bf2f(r1.x), acc[0]);
        acc[1] = fmaf(w1, bf2f(r1.y), acc[1]);
        acc[2] = fmaf(w1, bf2f(r1.z), acc[2]);
        acc[3] = fmaf(w1, bf2f(r1.w), acc[3]);
        acc[0] = fmaf(w2, bf2f(r2.x), acc[0]);
        acc[1] = fmaf(w2, bf2f(r2.y), acc[1]);
        acc[2] = fmaf(w2, bf2f(r2.z), acc[2]);
        acc[3] = fmaf(w2, bf2f(r2.w), acc[3]);
        acc[0] = fmaf(w3, bf2f(r3.x), acc[0]);
        acc[1] = fmaf(w3, bf2f(r3.y), acc[1]);
        acc[2] = fmaf(w3, bf2f(r3.z), acc[2]);
        acc[3] = fmaf(w3, bf2f(r3.w), acc[3]);
      } else {
        unsigned short r0 = h16[(size_t)s0 * HC_ + lane];
        unsigned short r1 = h16[(size_t)s1 * HC_ + lane];
        unsigned short r2 = h16[(size_t)s2 * HC_ + lane];
        unsigned short r3 = h16[(size_t)s3 * HC_ + lane];
        wsum += (w0 + w1) + (w2 + w3);
        acc[0] = fmaf(w0, bf2f(r0), acc[0]);
        acc[0] = fmaf(w1, bf2f(r1), acc[0]);
        acc[0] = fmaf(w2, bf2f(r2), acc[0]);
        acc[0] = fmaf(w3, bf2f(r3), acc[0]);
      }
    }
    for (; i < cnt; ++i) {
      int s0 = __shfl(s_l, i);
      float w0 = ldsW[wl][i * H_ + head];
      wsum += w0;
      if (FPL == 4) {
        ushort4 r0 = ((const ushort4*)(h16 + (size_t)s0 * HC_))[lane];
        acc[0] = fmaf(w0, bf2f(r0.x), acc[0]);
        acc[1] = fmaf(w0, bf2f(r0.y), acc[1]);
        acc[2] = fmaf(w0, bf2f(r0.z), acc[2]);
        acc[3] = fmaf(w0, bf2f(r0.w), acc[3]);
      } else {
        unsigned short r0 = h16[(size_t)s0 * HC_ + lane];
        acc[0] = fmaf(w0, bf2f(r0), acc[0]);
      }
    }
  }

  float inv = 1.0f / wsum;
  if (FPL == 4) {
    float4 o;
    o.x = acc[0] * inv; o.y = acc[1] * inv; o.z = acc[2] * inv; o.w = acc[3] * inv;
    if (bias) {
      const float4 b = ((const float4*)bias)[lane];
      o.x += b.x; o.y += b.y; o.z += b.z; o.w += b.w;
    }
    if (doElu) {
      o.x = o.x > 0.f ? o.x : expm1f(o.x);
      o.y = o.y > 0.f ? o.y : expm1f(o.y);
      o.z = o.z > 0.f ? o.z : expm1f(o.z);
      o.w = o.w > 0.f ? o.w : expm1f(o.w);
    }
    ((float4*)(outp + (size_t)wid * HC_))[lane] = o;
  } else {
    float o = acc[0] * inv;
    if (bias) o += bias[lane];
    if (doElu) o = o > 0.f ? o : expm1f(o);
    outp[(size_t)wid * HC_ + lane] = o;
  }
}

// ---------------- batch norm stats ----------------
__global__ __launch_bounds__(256) void bn_stats_kernel(const float* __restrict__ x, int N,
                                float* __restrict__ sums, float* __restrict__ sumsq)
{
  const int wid = threadIdx.x >> 6, lane = threadIdx.x & 63;
  const int gw = blockIdx.x * 4 + wid;
  const int tw = gridDim.x * 4;
  float4 s = make_float4(0.f, 0.f, 0.f, 0.f);
  float4 q = make_float4(0.f, 0.f, 0.f, 0.f);
#pragma unroll 4
  for (int r = gw; r < N; r += tw) {
    float4 v = ((const float4*)(x + (size_t)r * 256))[lane];
    s.x += v.x; s.y += v.y; s.z += v.z; s.w += v.w;
    q.x = fmaf(v.x, v.x, q.x); q.y = fmaf(v.y, v.y, q.y);
    q.z = fmaf(v.z, v.z, q.z); q.w = fmaf(v.w, v.w, q.w);
  }
  __shared__ float ls[4][512];
  *(float4*)&ls[wid][lane * 4] = s;
  *(float4*)&ls[wid][256 + lane * 4] = q;
  __syncthreads();
  const int t = threadIdx.x;
  float a = ls[0][t] + ls[1][t] + ls[2][t] + ls[3][t];
  float b = ls[0][t + 256] + ls[1][t + 256] + ls[2][t + 256] + ls[3][t + 256];
  atomicAdd(&sums[t], a);
  atomicAdd(&sumsq[t], b);
}

__global__ void bn_final_kernel(const float* __restrict__ sums, const float* __restrict__ sumsq,
                                const float* __restrict__ g, const float* __restrict__ be,
                                int N, float* __restrict__ scale, float* __restrict__ shift)
{
  int f = threadIdx.x;
  float mu = sums[f] / N;
  float var = sumsq[f] / N - mu * mu;
  float rs = rsqrtf(var + 1e-5f);
  float sc = g[f] * rs;
  scale[f] = sc;
  shift[f] = be[f] - mu * sc;
}

// ---------------- MLP head: thread-per-node, LDS weight broadcast ----------------
__global__ __launch_bounds__(256) void mlp_kernel(const float* __restrict__ h,
                           const float* __restrict__ fw1,
                           const float* __restrict__ fb1, const float* __restrict__ fw2,
                           const float* __restrict__ fb2, float* __restrict__ out, int N)
{
  __shared__ float w1s[64][32];
  __shared__ float w2s[32][2];
  __shared__ float b1s[32];
  const int t = threadIdx.x;
  for (int i = t; i < 64 * 32; i += 256) w1s[i >> 5][i & 31] = fw1[i];
  if (t < 64) w2s[t >> 1][t & 1] = fw2[t];
  if (t < 32) b1s[t] = fb1[t];
  __syncthreads();

  int n = blockIdx.x * 256 + t;
  if (n >= N) return;

  float hv[64];
#pragma unroll
  for (int k4 = 0; k4 < 16; ++k4) {
    float4 v = *(const float4*)(h + (size_t)n * 64 + k4 * 4);
    hv[k4 * 4 + 0] = v.x; hv[k4 * 4 + 1] = v.y;
    hv[k4 * 4 + 2] = v.z; hv[k4 * 4 + 3] = v.w;
  }
  float hid[32];
#pragma unroll
  for (int j = 0; j < 32; ++j) hid[j] = b1s[j];
#pragma unroll
  for (int k = 0; k < 64; ++k) {
    float hk = hv[k];
#pragma unroll
    for (int jb = 0; jb < 8; ++jb) {
      float4 wv = *(const float4*)&w1s[k][jb * 4];
      hid[jb * 4 + 0] = fmaf(hk, wv.x, hid[jb * 4 + 0]);
      hid[jb * 4 + 1] = fmaf(hk, wv.y, hid[jb * 4 + 1]);
      hid[jb * 4 + 2] = fmaf(hk, wv.z, hid[jb * 4 + 2]);
      hid[jb * 4 + 3] = fmaf(hk, wv.w, hid[jb * 4 + 3]);
    }
  }
  float p0 = fb2[0], p1 = fb2[1];
#pragma unroll
  for (int j = 0; j < 32; ++j) {
    float r = fmaxf(hid[j], 0.f);
    p0 = fmaf(r, w2s[j][0], p0);
    p1 = fmaf(r, w2s[j][1], p1);
  }
  *(float2*)(out + (size_t)n * 2) = make_float2(p0, p1);
}

// ---------------- host ----------------
extern "C" void kernel_launch(void* const* d_in, const int* in_sizes, int n_in,
                              void* d_out, int out_size, void* d_ws, size_t ws_size,
                              hipStream_t stream)
{
  const float* x   = (const float*)d_in[0];
  const int*   ei  = (const int*)d_in[1];
  const float* W1  = (const float*)d_in[2];
  const float* a1s = (const float*)d_in[3];
  const float* a1d = (const float*)d_in[4];
  const float* W2  = (const float*)d_in[6];
  const float* a2s = (const float*)d_in[7];
  const float* a2d = (const float*)d_in[8];
  const float* W3  = (const float*)d_in[10];
  const float* a3s = (const float*)d_in[11];
  const float* a3d = (const float*)d_in[12];
  const float* b3  = (const float*)d_in[13];
  const float* g1  = (const float*)d_in[14];
  const float* be1 = (const float*)d_in[15];
  const float* g2  = (const float*)d_in[16];
  const float* be2 = (const float*)d_in[17];
  const float* fw1 = (const float*)d_in[18];
  const float* fb1 = (const float*)d_in[19];
  const float* fw2 = (const float*)d_in[20];
  const float* fb2 = (const float*)d_in[21];
  float* out = (float*)d_out;

  const int F = 128;
  const int N = in_sizes[0] / F;
  const int E = in_sizes[1] / 2;
  const int Etot = E + N;
  const int* srcIdx = ei;
  const int* dstIdx = ei + E;

  char* w = (char*)d_ws;
  auto alloc = [&](size_t bytes) -> void* {
    void* p = (void*)w;
    w += (bytes + 255) & ~(size_t)255;
    return p;
  };
  unsigned short* h16 = (unsigned short*)alloc((size_t)N * 256 * 2);
  float* act     = (float*)alloc((size_t)N * 256 * 4);
  unsigned short* aHi = (unsigned short*)alloc((size_t)N * 256 * 2);
  unsigned short* aLo = (unsigned short*)alloc((size_t)N * 256 * 2);
  float* als     = (float*)alloc((size_t)N * 4 * 4);
  float* ald     = (float*)alloc((size_t)N * 4 * 4);
  int*   counts  = (int*)alloc((size_t)N * 4);
  int*   cursor  = (int*)alloc((size_t)N * 4);
  int*   rowStart= (int*)alloc((size_t)(N + 1) * 4);
  int*   csrSrc  = (int*)alloc((size_t)Etot * 4);
  int*   bsums   = (int*)alloc((size_t)((N + 255) / 256) * 4);
  float* sums    = (float*)alloc(256 * 4);
  float* sumsq   = (float*)alloc(256 * 4);
  float* scale1  = (float*)alloc(256 * 4);
  float* shift1  = (float*)alloc(256 * 4);
  float* scale2  = (float*)alloc(256 * 4);
  float* shift2  = (float*)alloc(256 * 4);
  unsigned short* w1h = (unsigned short*)alloc((size_t)128 * 256 * 2);
  unsigned short* w1l = (unsigned short*)alloc((size_t)128 * 256 * 2);
  unsigned short* w2h = (unsigned short*)alloc((size_t)256 * 256 * 2);
  unsigned short* w2l = (unsigned short*)alloc((size_t)256 * 256 * 2);
  unsigned short* w3h = (unsigned short*)alloc((size_t)256 * 64 * 2);
  unsigned short* w3l = (unsigned short*)alloc((size_t)256 * 64 * 2);

  const int nb = (N + 255) / 256;
  const int ebk = (Etot + 255) / 256;
  const int aggBlocks = (N + 3) / 4;

  // ---- weight prep ----
  wprep_kernel<<<(128 * 256 + 255) / 256, 256, 0, stream>>>(W1, w1h, w1l, 128, 256);
  wprep_kernel<<<(256 * 256 + 255) / 256, 256, 0, stream>>>(W2, w2h, w2l, 256, 256);
  wprep_kernel<<<(256 * 64 + 255) / 256, 256, 0, stream>>>(W3, w3h, w3l, 256, 64);

  // ---- CSR build ----
  hipMemsetAsync(counts, 0, (size_t)N * 4, stream);
  hipMemsetAsync(cursor, 0, (size_t)N * 4, stream);
  count_kernel<<<ebk, 256, 0, stream>>>(dstIdx, E, Etot, counts);
  block_sum_kernel<<<nb, 256, 0, stream>>>(counts, N, bsums);
  scan_bsums_kernel<<<1, 256, 0, stream>>>(bsums, nb);
  scan_write_kernel<<<nb, 256, 0, stream>>>(counts, N, bsums, rowStart, Etot);
  fill_kernel<<<ebk, 256, 0, stream>>>(srcIdx, dstIdx, E, Etot, rowStart, cursor, csrSrc);

  dim3 g12((N + 63) / 64, 1);
  dim3 g3((N + 255) / 256, 1);

  // ---- GAT layer 1 ----
  split_kernel<<<2048, 256, 0, stream>>>(x, aHi, aLo, (size_t)N * 128 / 4);
  gemm_al<1, 4, 4, 4><<<g12, 256, 0, stream>>>(aHi, aLo, w1h, w1l, a1s, a1d, h16, als, ald, N);
  aggregate_fused<256><<<aggBlocks, 256, 0, stream>>>(h16, als, ald, csrSrc, rowStart, act, N, nullptr, 0);
  hipMemsetAsync(sums, 0, 256 * 4, stream);
  hipMemsetAsync(sumsq, 0, 256 * 4, stream);
  bn_stats_kernel<<<512, 256, 0, stream>>>(act, N, sums, sumsq);
  bn_final_kernel<<<1, 256, 0, stream>>>(sums, sumsq, g1, be1, N, scale1, shift1);

  // ---- GAT layer 2 ----
  bnsplit_kernel<<<2048, 256, 0, stream>>>(act, scale1, shift1, aHi, aLo, (size_t)N * 256 / 4);
  gemm_al<1, 4, 8, 4><<<g12, 256, 0, stream>>>(aHi, aLo, w2h, w2l, a2s, a2d, h16, als, ald, N);
  aggregate_fused<256><<<aggBlocks, 256, 0, stream>>>(h16, als, ald, csrSrc, rowStart, act, N, nullptr, 0);
  hipMemsetAsync(sums, 0, 256 * 4, stream);
  hipMemsetAsync(sumsq, 0, 256 * 4, stream);
  bn_stats_kernel<<<512, 256, 0, stream>>>(act, N, sums, sumsq);
  bn_final_kernel<<<1, 256, 0, stream>>>(sums, sumsq, g2, be2, N, scale2, shift2);

  // ---- GAT layer 3 ----
  bnsplit_kernel<<<2048, 256, 0, stream>>>(act, scale2, shift2, aHi, aLo, (size_t)N * 256 / 4);
  gemm_al<4, 1, 8, 1><<<g3, 256, 0, stream>>>(aHi, aLo, w3h, w3l, a3s, a3d, h16, als, ald, N);
  aggregate_fused<64><<<aggBlocks, 256, 0, stream>>>(h16, als, ald, csrSrc, rowStart, act, N, b3, 1);

  // ---- MLP head ----
  mlp_kernel<<<(N + 255) / 256, 256, 0, stream>>>(act, fw1, fb1, fw2, fb2, out, N);
}

// Round 10
// 346.309 us; speedup vs baseline: 1.2941x; 1.0853x over previous
//
#include <hip/hip_runtime.h>
#include <math.h>
#include <stdint.h>

typedef __attribute__((ext_vector_type(8))) short short8v;
typedef __attribute__((ext_vector_type(4))) float float4v;

__device__ __forceinline__ float bf2f(unsigned short u) {
  return __uint_as_float((unsigned int)u << 16);
}
__device__ __forceinline__ unsigned short f2bf(float f) {   // RNE
  unsigned int u = __float_as_uint(f);
  unsigned int r = (u + 0x7FFFu + ((u >> 16) & 1u)) >> 16;
  return (unsigned short)r;
}
__device__ __forceinline__ float exp_lrelu(float x) {
  x = x > 0.f ? x : 0.2f * x;
  return expf(x);       // softmax shift-invariant: segment-max skipped
}

typedef __attribute__((address_space(3))) void lds_void;
typedef const __attribute__((address_space(1))) void glb_void;
__device__ __forceinline__ void gload_lds16(const void* g, void* l) {
  __builtin_amdgcn_global_load_lds((glb_void*)g, (lds_void*)l, 16, 0, 0);
}

// ---------------- weight prep: fp32 W[K][Nw] -> hi/lo bf16 in MFMA-frag order ----
__global__ void wprep_kernel(const float* __restrict__ W, unsigned short* __restrict__ Wh,
                             unsigned short* __restrict__ Wl, int K, int Nw)
{
  int t = blockIdx.x * 256 + threadIdx.x;
  if (t >= K * Nw) return;
  int i = t & 7;
  int lane = (t >> 3) & 63;
  int frag = t >> 9;
  int ktiles = K >> 5;
  int n_tile = frag / ktiles, k_tile = frag - n_tile * ktiles;
  int k = k_tile * 32 + ((lane >> 4) << 3) + i;
  int n = (n_tile << 4) + (lane & 15);
  float v = W[(size_t)k * Nw + n];
  unsigned short hi = (unsigned short)(__float_as_uint(v) >> 16);   // trunc
  float rem = v - bf2f(hi);
  Wh[t] = hi;
  Wl[t] = f2bf(rem);
}

// ---------------- A-side split: x fp32 -> hi/lo bf16 ----------------
__global__ __launch_bounds__(256) void split_kernel(const float* __restrict__ in,
    unsigned short* __restrict__ hi, unsigned short* __restrict__ lo, size_t n4)
{
  size_t i0 = (size_t)blockIdx.x * 256 + threadIdx.x;
  size_t stride = (size_t)gridDim.x * 256;
  for (size_t idx = i0; idx < n4; idx += stride) {
    float4 v = ((const float4*)in)[idx];
    float vv[4] = {v.x, v.y, v.z, v.w};
    ushort4 h, l;
    unsigned short* hp = &h.x; unsigned short* lp = &l.x;
#pragma unroll
    for (int j = 0; j < 4; ++j) {
      unsigned short hh = (unsigned short)(__float_as_uint(vv[j]) >> 16);
      hp[j] = hh;
      lp[j] = f2bf(vv[j] - bf2f(hh));
    }
    ((ushort4*)hi)[idx] = h;
    ((ushort4*)lo)[idx] = l;
  }
}

// BN + ELU + split, reading bf16 act: act16 [N][256] -> hi/lo bf16
__global__ __launch_bounds__(256) void bnsplit_kernel(const unsigned short* __restrict__ act,
    const float* __restrict__ scale, const float* __restrict__ shift,
    unsigned short* __restrict__ hi, unsigned short* __restrict__ lo, size_t nchunks)
{
  size_t i0 = (size_t)blockIdx.x * 256 + threadIdx.x;
  size_t stride = (size_t)gridDim.x * 256;
  for (size_t idx = i0; idx < nchunks; idx += stride) {
    ushort4 u = ((const ushort4*)act)[idx];
    int f = (int)((idx * 4) & 255);
    float4 sc = *(const float4*)(scale + f);
    float4 sh = *(const float4*)(shift + f);
    float vv[4];
    vv[0] = fmaf(bf2f(u.x), sc.x, sh.x);
    vv[1] = fmaf(bf2f(u.y), sc.y, sh.y);
    vv[2] = fmaf(bf2f(u.z), sc.z, sh.z);
    vv[3] = fmaf(bf2f(u.w), sc.w, sh.w);
    ushort4 h, l;
    unsigned short* hp = &h.x; unsigned short* lp = &l.x;
#pragma unroll
    for (int j = 0; j < 4; ++j) {
      float t = vv[j];
      t = t > 0.f ? t : expm1f(t);                 // ELU
      unsigned short hh = (unsigned short)(__float_as_uint(t) >> 16);
      hp[j] = hh;
      lp[j] = f2bf(t - bf2f(hh));
    }
    ((ushort4*)hi)[idx] = h;
    ((ushort4*)lo)[idx] = l;
  }
}

// ---------------- MFMA GEMM + fused al epilogue, LDS-staged A ----------------
// A staged per K-step (BK=32) via global_load_lds(16B), double-buffered.
// LDS layout per half-tile: [group(64rows)][chunk(8k)][row] -> off = g*4096 + c*1024 + r*16.
// Wave wid stages chunk wid (uniform LDS base + lane*16, row=lane). B register-direct (L2-hot).
template<int MI, int WM, int WN, int KTILES, int HEADS>
__global__ __launch_bounds__(256) void gemm_al(
    const unsigned short* __restrict__ Ah, const unsigned short* __restrict__ Al,
    const unsigned short* __restrict__ Bh, const unsigned short* __restrict__ Bl,
    const float* __restrict__ a_s, const float* __restrict__ a_d,
    unsigned short* __restrict__ C, float* __restrict__ al_s, float* __restrict__ al_d,
    int M)
{
  constexpr int BM = WM * MI * 16;
  constexpr int NG = BM / 64;            // 64-row groups per tile
  constexpr int TILEB = BM * 64;         // bytes per (hi or lo) half-tile
  constexpr int Nw = WN * 64, K = KTILES * 32;
  __shared__ __align__(16) unsigned char smem[2][2][TILEB];

  const int wid = threadIdx.x >> 6, lane = threadIdx.x & 63;
  const int wm = wid / WN, wn = wid % WN;
  const int m0 = blockIdx.x * BM;
  const int n0 = wn * 64;
  const int ar = lane & 15;
  const int cchunk = lane >> 4;
  const int ntile0 = n0 >> 4;

  float4v acc[MI][4];
#pragma unroll
  for (int mi = 0; mi < MI; ++mi)
#pragma unroll
    for (int ni = 0; ni < 4; ++ni)
      acc[mi][ni] = (float4v){0.f, 0.f, 0.f, 0.f};

  auto stage = [&](int buf, int kt) {
    const int kk = kt * 32;
#pragma unroll
    for (int i = 0; i < NG; ++i) {
      const unsigned short* gh = Ah + (size_t)(m0 + i * 64 + lane) * K + kk + wid * 8;
      const unsigned short* gl = Al + (size_t)(m0 + i * 64 + lane) * K + kk + wid * 8;
      gload_lds16(gh, &smem[buf][0][i * 4096 + wid * 1024]);
      gload_lds16(gl, &smem[buf][1][i * 4096 + wid * 1024]);
    }
  };

  stage(0, 0);
  int cur = 0;
  for (int kt = 0; kt < KTILES; ++kt) {
    __syncthreads();    // drains vmcnt (stage complete) + lgkm; handoff of buffers
    // B fragments for kt (issued first so their vmcnt retires before the stage loads)
    short8v bh[4], bl[4];
#pragma unroll
    for (int ni = 0; ni < 4; ++ni) {
      size_t off = (((size_t)(ntile0 + ni) * KTILES + kt) * 64 + lane) * 8;
      bh[ni] = *(const short8v*)(Bh + off);
      bl[ni] = *(const short8v*)(Bl + off);
    }
    // stage next tile (stays in flight under this step's MFMAs)
    if (kt + 1 < KTILES) stage(cur ^ 1, kt + 1);
    // A fragments from LDS
    short8v ah[MI], al_[MI];
#pragma unroll
    for (int mi = 0; mi < MI; ++mi) {
      int row = wm * MI * 16 + mi * 16 + ar;
      int off = (row >> 6) * 4096 + cchunk * 1024 + (row & 63) * 16;
      ah[mi] = *(const short8v*)&smem[cur][0][off];
      al_[mi] = *(const short8v*)&smem[cur][1][off];
    }
#pragma unroll
    for (int mi = 0; mi < MI; ++mi)
#pragma unroll
      for (int ni = 0; ni < 4; ++ni) {
        acc[mi][ni] = __builtin_amdgcn_mfma_f32_16x16x32_bf16(ah[mi], bh[ni], acc[mi][ni], 0, 0, 0);
        acc[mi][ni] = __builtin_amdgcn_mfma_f32_16x16x32_bf16(ah[mi], bl[ni], acc[mi][ni], 0, 0, 0);
        acc[mi][ni] = __builtin_amdgcn_mfma_f32_16x16x32_bf16(al_[mi], bh[ni], acc[mi][ni], 0, 0, 0);
      }
    cur ^= 1;
  }

  const int cc = lane & 15;
#pragma unroll
  for (int mi = 0; mi < MI; ++mi) {
    int rowb = m0 + wm * MI * 16 + mi * 16 + ((lane >> 4) << 2);
#pragma unroll
    for (int r = 0; r < 4; ++r) {
      int row = rowb + r;
      if (row < M) {
#pragma unroll
        for (int ni = 0; ni < 4; ++ni)
          C[(size_t)row * Nw + n0 + ni * 16 + cc] = f2bf(acc[mi][ni][r]);
      }
    }
  }

  // fused attention-logit epilogue (bf16-rounded h, matches downstream consumption)
  const int head = (HEADS == 4) ? wn : 0;
  float as_[4], ad_[4];
#pragma unroll
  for (int ni = 0; ni < 4; ++ni) {
    as_[ni] = a_s[head * 64 + ni * 16 + cc];
    ad_[ni] = a_d[head * 64 + ni * 16 + cc];
  }
#pragma unroll
  for (int mi = 0; mi < MI; ++mi) {
#pragma unroll
    for (int r = 0; r < 4; ++r) {
      float h0 = bf2f(f2bf(acc[mi][0][r]));
      float h1 = bf2f(f2bf(acc[mi][1][r]));
      float h2 = bf2f(f2bf(acc[mi][2][r]));
      float h3 = bf2f(f2bf(acc[mi][3][r]));
      float ps = h0 * as_[0] + h1 * as_[1] + h2 * as_[2] + h3 * as_[3];
      float pd = h0 * ad_[0] + h1 * ad_[1] + h2 * ad_[2] + h3 * ad_[3];
#pragma unroll
      for (int off = 1; off < 16; off <<= 1) {
        ps += __shfl_xor(ps, off);
        pd += __shfl_xor(pd, off);
      }
      int row = m0 + wm * MI * 16 + mi * 16 + ((lane >> 4) << 2) + r;
      if (cc == 0 && row < M) {
        al_s[row * HEADS + head] = ps;
        al_d[row * HEADS + head] = pd;
      }
    }
  }
}

// ---------------- CSR build ----------------
__global__ void count_kernel(const int* __restrict__ dst, int E, int Etot, int* __restrict__ counts)
{
  int e = blockIdx.x * 256 + threadIdx.x;
  if (e >= Etot) return;
  int d = (e < E) ? dst[e] : (e - E);
  atomicAdd(&counts[d], 1);
}

__global__ void block_sum_kernel(const int* __restrict__ counts, int N, int* __restrict__ bsums)
{
  __shared__ int sd[256];
  int i = blockIdx.x * 256 + threadIdx.x;
  sd[threadIdx.x] = (i < N) ? counts[i] : 0;
  __syncthreads();
  for (int off = 128; off; off >>= 1) {
    if (threadIdx.x < off) sd[threadIdx.x] += sd[threadIdx.x + off];
    __syncthreads();
  }
  if (threadIdx.x == 0) bsums[blockIdx.x] = sd[0];
}

__global__ void scan_bsums_kernel(int* bsums, int nb)
{
  __shared__ int sd[256];
  int t = threadIdx.x;
  int v = (t < nb) ? bsums[t] : 0;
  sd[t] = v;
  __syncthreads();
  for (int off = 1; off < 256; off <<= 1) {
    int x = (t >= off) ? sd[t - off] : 0;
    __syncthreads();
    sd[t] += x;
    __syncthreads();
  }
  if (t < nb) bsums[t] = sd[t] - v;  // exclusive
}

__global__ void scan_write_kernel(const int* __restrict__ counts, int N,
                                  const int* __restrict__ bsums, int* __restrict__ rowStart, int Etot)
{
  __shared__ int sd[256];
  int i = blockIdx.x * 256 + threadIdx.x;
  int v = (i < N) ? counts[i] : 0;
  sd[threadIdx.x] = v;
  __syncthreads();
  for (int off = 1; off < 256; off <<= 1) {
    int x = (threadIdx.x >= off) ? sd[threadIdx.x - off] : 0;
    __syncthreads();
    sd[threadIdx.x] += x;
    __syncthreads();
  }
  if (i < N) rowStart[i] = bsums[blockIdx.x] + sd[threadIdx.x] - v;  // exclusive
  if (i == N - 1) rowStart[N] = Etot;
}

__global__ void fill_kernel(const int* __restrict__ src, const int* __restrict__ dst,
                            int E, int Etot, const int* __restrict__ rowStart,
                            int* __restrict__ cursor, int* __restrict__ csrSrc)
{
  int e = blockIdx.x * 256 + threadIdx.x;
  if (e >= Etot) return;
  int s, d;
  if (e < E) { s = src[e]; d = dst[e]; } else { s = d = e - E; }
  int pos = rowStart[d] + atomicAdd(&cursor[d], 1);
  csrSrc[pos] = s;
}

// ---------------- fused aggregation (edge weights inline); OUT16 -> bf16 output ----
template<int HC_, bool OUT16>
__global__ __launch_bounds__(256) void aggregate_fused(
    const unsigned short* __restrict__ h16,
    const float* __restrict__ als, const float* __restrict__ ald,
    const int* __restrict__ csrSrc, const int* __restrict__ rowStart,
    void* __restrict__ outp, int N, const float* __restrict__ bias, int doElu)
{
  constexpr int H_ = HC_ / 64;
  constexpr int FPL = HC_ / 64;
  __shared__ float ldsW[4][64 * H_];
  const int wl = threadIdx.x >> 6;
  int wid = blockIdx.x * 4 + wl;
  if (wid >= N) return;
  const int lane = threadIdx.x & 63;
  const int head = (H_ == 4) ? (lane >> 4) : 0;
  const int start = rowStart[wid], end = rowStart[wid + 1];

  float ad0, ad1, ad2, ad3;
  if (H_ == 4) {
    float4 adv = ((const float4*)ald)[wid];
    ad0 = adv.x; ad1 = adv.y; ad2 = adv.z; ad3 = adv.w;
  } else {
    ad0 = ald[wid]; ad1 = ad2 = ad3 = 0.f;
  }

  float acc[FPL] = {};
  float wsum = 0.f;

  for (int base = start; base < end; base += 64) {
    int cnt = end - base; if (cnt > 64) cnt = 64;
    int s_l = 0;
    if (lane < cnt) {
      s_l = csrSrc[base + lane];
      if (H_ == 4) {
        float4 av = ((const float4*)als)[s_l];
        float4 w4;
        w4.x = exp_lrelu(av.x + ad0);
        w4.y = exp_lrelu(av.y + ad1);
        w4.z = exp_lrelu(av.z + ad2);
        w4.w = exp_lrelu(av.w + ad3);
        *(float4*)&ldsW[wl][lane * 4] = w4;
      } else {
        ldsW[wl][lane] = exp_lrelu(als[s_l] + ad0);
      }
    }
    int i = 0;
    for (; i + 4 <= cnt; i += 4) {
      int s0 = __shfl(s_l, i);
      int s1 = __shfl(s_l, i + 1);
      int s2 = __shfl(s_l, i + 2);
      int s3 = __shfl(s_l, i + 3);
      float w0 = ldsW[wl][(i + 0) * H_ + head];
      float w1 = ldsW[wl][(i + 1) * H_ + head];
      float w2 = ldsW[wl][(i + 2) * H_ + head];
      float w3 = ldsW[wl][(i + 3) * H_ + head];
      if (FPL == 4) {
        ushort4 r0 = ((const ushort4*)(h16 + (size_t)s0 * HC_))[lane];
        ushort4 r1 = ((const ushort4*)(h16 + (size_t)s1 * HC_))[lane];
        ushort4 r2 = ((const ushort4*)(h16 + (size_t)s2 * HC_))[lane];
        ushort4 r3 = ((const ushort4*)(h16 + (size_t)s3 * HC_))[lane];
        wsum += (w0 + w1) + (w2 + w3);
        acc[0] = fmaf(w0, bf2f(r0.x), acc[0]);
        acc[1] = fmaf(w0, bf2f(r0.y), acc[1]);
        acc[2] = fmaf(w0, bf2f(r0.z), acc[2]);
        acc[3] = fmaf(w0, bf2f(r0.w), acc[3]);
        acc[0] = fmaf(w1, bf2f(r1.x), acc[0]);
        acc[1] = fmaf(w1, bf2f(r1.y), acc[1]);
        acc[2] = fmaf(w1, bf2f(r1.z), acc[2]);
        acc[3] = fmaf(w1, bf2f(r1.w), acc[3]);
        acc[0] = fmaf(w2, bf2f(r2.x), acc[0]);
        acc[1] = fmaf(w2, bf2f(r2.y), acc[1]);
        acc[2] = fmaf(w2, bf2f(r2.z), acc[2]);
        acc[3] = fmaf(w2, bf2f(r2.w), acc[3]);
        acc[0] = fmaf(w3, bf2f(r3.x), acc[0]);
        acc[1] = fmaf(w3, bf2f(r3.y), acc[1]);
        acc[2] = fmaf(w3, bf2f(r3.z), acc[2]);
        acc[3] = fmaf(w3, bf2f(r3.w), acc[3]);
      } else {
        unsigned short r0 = h16[(size_t)s0 * HC_ + lane];
        unsigned short r1 = h16[(size_t)s1 * HC_ + lane];
        unsigned short r2 = h16[(size_t)s2 * HC_ + lane];
        unsigned short r3 = h16[(size_t)s3 * HC_ + lane];
        wsum += (w0 + w1) + (w2 + w3);
        acc[0] = fmaf(w0, bf2f(r0), acc[0]);
        acc[0] = fmaf(w1, bf2f(r1), acc[0]);
        acc[0] = fmaf(w2, bf2f(r2), acc[0]);
        acc[0] = fmaf(w3, bf2f(r3), acc[0]);
      }
    }
    for (; i < cnt; ++i) {
      int s0 = __shfl(s_l, i);
      float w0 = ldsW[wl][i * H_ + head];
      wsum += w0;
      if (FPL == 4) {
        ushort4 r0 = ((const ushort4*)(h16 + (size_t)s0 * HC_))[lane];
        acc[0] = fmaf(w0, bf2f(r0.x), acc[0]);
        acc[1] = fmaf(w0, bf2f(r0.y), acc[1]);
        acc[2] = fmaf(w0, bf2f(r0.z), acc[2]);
        acc[3] = fmaf(w0, bf2f(r0.w), acc[3]);
      } else {
        unsigned short r0 = h16[(size_t)s0 * HC_ + lane];
        acc[0] = fmaf(w0, bf2f(r0), acc[0]);
      }
    }
  }

  float inv = 1.0f / wsum;
  if (FPL == 4) {
    float o0 = acc[0] * inv, o1 = acc[1] * inv, o2 = acc[2] * inv, o3 = acc[3] * inv;
    if (bias) {
      const float4 b = ((const float4*)bias)[lane];
      o0 += b.x; o1 += b.y; o2 += b.z; o3 += b.w;
    }
    if (doElu) {
      o0 = o0 > 0.f ? o0 : expm1f(o0);
      o1 = o1 > 0.f ? o1 : expm1f(o1);
      o2 = o2 > 0.f ? o2 : expm1f(o2);
      o3 = o3 > 0.f ? o3 : expm1f(o3);
    }
    if (OUT16) {
      ushort4 o;
      o.x = f2bf(o0); o.y = f2bf(o1); o.z = f2bf(o2); o.w = f2bf(o3);
      ((ushort4*)((unsigned short*)outp + (size_t)wid * HC_))[lane] = o;
    } else {
      ((float4*)((float*)outp + (size_t)wid * HC_))[lane] = make_float4(o0, o1, o2, o3);
    }
  } else {
    float o = acc[0] * inv;
    if (bias) o += bias[lane];
    if (doElu) o = o > 0.f ? o : expm1f(o);
    if (OUT16) ((unsigned short*)outp)[(size_t)wid * HC_ + lane] = f2bf(o);
    else       ((float*)outp)[(size_t)wid * HC_ + lane] = o;
  }
}

// ---------------- batch norm stats over bf16 act ----------------
__global__ __launch_bounds__(256) void bn_stats_kernel(const unsigned short* __restrict__ x, int N,
                                float* __restrict__ sums, float* __restrict__ sumsq)
{
  const int wid = threadIdx.x >> 6, lane = threadIdx.x & 63;
  const int gw = blockIdx.x * 4 + wid;
  const int tw = gridDim.x * 4;
  float4 s = make_float4(0.f, 0.f, 0.f, 0.f);
  float4 q = make_float4(0.f, 0.f, 0.f, 0.f);
#pragma unroll 4
  for (int r = gw; r < N; r += tw) {
    ushort4 u = ((const ushort4*)(x + (size_t)r * 256))[lane];
    float v0 = bf2f(u.x), v1 = bf2f(u.y), v2 = bf2f(u.z), v3 = bf2f(u.w);
    s.x += v0; s.y += v1; s.z += v2; s.w += v3;
    q.x = fmaf(v0, v0, q.x); q.y = fmaf(v1, v1, q.y);
    q.z = fmaf(v2, v2, q.z); q.w = fmaf(v3, v3, q.w);
  }
  __shared__ float ls[4][512];
  *(float4*)&ls[wid][lane * 4] = s;
  *(float4*)&ls[wid][256 + lane * 4] = q;
  __syncthreads();
  const int t = threadIdx.x;
  float a = ls[0][t] + ls[1][t] + ls[2][t] + ls[3][t];
  float b = ls[0][t + 256] + ls[1][t + 256] + ls[2][t + 256] + ls[3][t + 256];
  atomicAdd(&sums[t], a);
  atomicAdd(&sumsq[t], b);
}

__global__ void bn_final_kernel(const float* __restrict__ sums, const float* __restrict__ sumsq,
                                const float* __restrict__ g, const float* __restrict__ be,
                                int N, float* __restrict__ scale, float* __restrict__ shift)
{
  int f = threadIdx.x;
  float mu = sums[f] / N;
  float var = sumsq[f] / N - mu * mu;
  float rs = rsqrtf(var + 1e-5f);
  float sc = g[f] * rs;
  scale[f] = sc;
  shift[f] = be[f] - mu * sc;
}

// ---------------- MLP head: thread-per-node, LDS weight broadcast ----------------
__global__ __launch_bounds__(256) void mlp_kernel(const float* __restrict__ h,
                           const float* __restrict__ fw1,
                           const float* __restrict__ fb1, const float* __restrict__ fw2,
                           const float* __restrict__ fb2, float* __restrict__ out, int N)
{
  __shared__ float w1s[64][32];
  __shared__ float w2s[32][2];
  __shared__ float b1s[32];
  const int t = threadIdx.x;
  for (int i = t; i < 64 * 32; i += 256) w1s[i >> 5][i & 31] = fw1[i];
  if (t < 64) w2s[t >> 1][t & 1] = fw2[t];
  if (t < 32) b1s[t] = fb1[t];
  __syncthreads();

  int n = blockIdx.x * 256 + t;
  if (n >= N) return;

  float hv[64];
#pragma unroll
  for (int k4 = 0; k4 < 16; ++k4) {
    float4 v = *(const float4*)(h + (size_t)n * 64 + k4 * 4);
    hv[k4 * 4 + 0] = v.x; hv[k4 * 4 + 1] = v.y;
    hv[k4 * 4 + 2] = v.z; hv[k4 * 4 + 3] = v.w;
  }
  float hid[32];
#pragma unroll
  for (int j = 0; j < 32; ++j) hid[j] = b1s[j];
#pragma unroll
  for (int k = 0; k < 64; ++k) {
    float hk = hv[k];
#pragma unroll
    for (int jb = 0; jb < 8; ++jb) {
      float4 wv = *(const float4*)&w1s[k][jb * 4];
      hid[jb * 4 + 0] = fmaf(hk, wv.x, hid[jb * 4 + 0]);
      hid[jb * 4 + 1] = fmaf(hk, wv.y, hid[jb * 4 + 1]);
      hid[jb * 4 + 2] = fmaf(hk, wv.z, hid[jb * 4 + 2]);
      hid[jb * 4 + 3] = fmaf(hk, wv.w, hid[jb * 4 + 3]);
    }
  }
  float p0 = fb2[0], p1 = fb2[1];
#pragma unroll
  for (int j = 0; j < 32; ++j) {
    float r = fmaxf(hid[j], 0.f);
    p0 = fmaf(r, w2s[j][0], p0);
    p1 = fmaf(r, w2s[j][1], p1);
  }
  *(float2*)(out + (size_t)n * 2) = make_float2(p0, p1);
}

// ---------------- host ----------------
extern "C" void kernel_launch(void* const* d_in, const int* in_sizes, int n_in,
                              void* d_out, int out_size, void* d_ws, size_t ws_size,
                              hipStream_t stream)
{
  const float* x   = (const float*)d_in[0];
  const int*   ei  = (const int*)d_in[1];
  const float* W1  = (const float*)d_in[2];
  const float* a1s = (const float*)d_in[3];
  const float* a1d = (const float*)d_in[4];
  const float* W2  = (const float*)d_in[6];
  const float* a2s = (const float*)d_in[7];
  const float* a2d = (const float*)d_in[8];
  const float* W3  = (const float*)d_in[10];
  const float* a3s = (const float*)d_in[11];
  const float* a3d = (const float*)d_in[12];
  const float* b3  = (const float*)d_in[13];
  const float* g1  = (const float*)d_in[14];
  const float* be1 = (const float*)d_in[15];
  const float* g2  = (const float*)d_in[16];
  const float* be2 = (const float*)d_in[17];
  const float* fw1 = (const float*)d_in[18];
  const float* fb1 = (const float*)d_in[19];
  const float* fw2 = (const float*)d_in[20];
  const float* fb2 = (const float*)d_in[21];
  float* out = (float*)d_out;

  const int F = 128;
  const int N = in_sizes[0] / F;
  const int E = in_sizes[1] / 2;
  const int Etot = E + N;
  const int* srcIdx = ei;
  const int* dstIdx = ei + E;

  char* w = (char*)d_ws;
  auto alloc = [&](size_t bytes) -> void* {
    void* p = (void*)w;
    w += (bytes + 255) & ~(size_t)255;
    return p;
  };
  unsigned short* h16  = (unsigned short*)alloc((size_t)N * 256 * 2);
  unsigned short* act16= (unsigned short*)alloc((size_t)N * 256 * 2);
  float* actf    = (float*)alloc((size_t)N * 64 * 4);
  unsigned short* aHi = (unsigned short*)alloc((size_t)N * 256 * 2);
  unsigned short* aLo = (unsigned short*)alloc((size_t)N * 256 * 2);
  float* als     = (float*)alloc((size_t)N * 4 * 4);
  float* ald     = (float*)alloc((size_t)N * 4 * 4);
  int*   counts  = (int*)alloc((size_t)N * 4);
  int*   cursor  = (int*)alloc((size_t)N * 4);
  int*   rowStart= (int*)alloc((size_t)(N + 1) * 4);
  int*   csrSrc  = (int*)alloc((size_t)Etot * 4);
  int*   bsums   = (int*)alloc((size_t)((N + 255) / 256) * 4);
  float* sums    = (float*)alloc(256 * 4);
  float* sumsq   = (float*)alloc(256 * 4);
  float* scale1  = (float*)alloc(256 * 4);
  float* shift1  = (float*)alloc(256 * 4);
  float* scale2  = (float*)alloc(256 * 4);
  float* shift2  = (float*)alloc(256 * 4);
  unsigned short* w1h = (unsigned short*)alloc((size_t)128 * 256 * 2);
  unsigned short* w1l = (unsigned short*)alloc((size_t)128 * 256 * 2);
  unsigned short* w2h = (unsigned short*)alloc((size_t)256 * 256 * 2);
  unsigned short* w2l = (unsigned short*)alloc((size_t)256 * 256 * 2);
  unsigned short* w3h = (unsigned short*)alloc((size_t)256 * 64 * 2);
  unsigned short* w3l = (unsigned short*)alloc((size_t)256 * 64 * 2);
  // slack so OOB staging reads of the last GEMM block stay in-bounds
  (void)alloc(65536);

  const int nb = (N + 255) / 256;
  const int ebk = (Etot + 255) / 256;
  const int aggBlocks = (N + 3) / 4;

  // ---- weight prep ----
  wprep_kernel<<<(128 * 256 + 255) / 256, 256, 0, stream>>>(W1, w1h, w1l, 128, 256);
  wprep_kernel<<<(256 * 256 + 255) / 256, 256, 0, stream>>>(W2, w2h, w2l, 256, 256);
  wprep_kernel<<<(256 * 64 + 255) / 256, 256, 0, stream>>>(W3, w3h, w3l, 256, 64);

  // ---- CSR build ----
  hipMemsetAsync(counts, 0, (size_t)N * 4, stream);
  hipMemsetAsync(cursor, 0, (size_t)N * 4, stream);
  count_kernel<<<ebk, 256, 0, stream>>>(dstIdx, E, Etot, counts);
  block_sum_kernel<<<nb, 256, 0, stream>>>(counts, N, bsums);
  scan_bsums_kernel<<<1, 256, 0, stream>>>(bsums, nb);
  scan_write_kernel<<<nb, 256, 0, stream>>>(counts, N, bsums, rowStart, Etot);
  fill_kernel<<<ebk, 256, 0, stream>>>(srcIdx, dstIdx, E, Etot, rowStart, cursor, csrSrc);

  dim3 g12((N + 63) / 64, 1);      // layers 1,2: MI=4, WM=1, WN=4 (BM=64, BN=256)
  dim3 g3((N + 127) / 128, 1);     // layer 3:   MI=2, WM=4, WN=1 (BM=128, BN=64)

  // ---- GAT layer 1 ----
  split_kernel<<<2048, 256, 0, stream>>>(x, aHi, aLo, (size_t)N * 128 / 4);
  gemm_al<4, 1, 4, 4, 4><<<g12, 256, 0, stream>>>(aHi, aLo, w1h, w1l, a1s, a1d, h16, als, ald, N);
  aggregate_fused<256, true><<<aggBlocks, 256, 0, stream>>>(h16, als, ald, csrSrc, rowStart, act16, N, nullptr, 0);
  hipMemsetAsync(sums, 0, 256 * 4, stream);
  hipMemsetAsync(sumsq, 0, 256 * 4, stream);
  bn_stats_kernel<<<512, 256, 0, stream>>>(act16, N, sums, sumsq);
  bn_final_kernel<<<1, 256, 0, stream>>>(sums, sumsq, g1, be1, N, scale1, shift1);

  // ---- GAT layer 2 ----
  bnsplit_kernel<<<2048, 256, 0, stream>>>(act16, scale1, shift1, aHi, aLo, (size_t)N * 64);
  gemm_al<4, 1, 4, 8, 4><<<g12, 256, 0, stream>>>(aHi, aLo, w2h, w2l, a2s, a2d, h16, als, ald, N);
  aggregate_fused<256, true><<<aggBlocks, 256, 0, stream>>>(h16, als, ald, csrSrc, rowStart, act16, N, nullptr, 0);
  hipMemsetAsync(sums, 0, 256 * 4, stream);
  hipMemsetAsync(sumsq, 0, 256 * 4, stream);
  bn_stats_kernel<<<512, 256, 0, stream>>>(act16, N, sums, sumsq);
  bn_final_kernel<<<1, 256, 0, stream>>>(sums, sumsq, g2, be2, N, scale2, shift2);

  // ---- GAT layer 3 ----
  bnsplit_kernel<<<2048, 256, 0, stream>>>(act16, scale2, shift2, aHi, aLo, (size_t)N * 64);
  gemm_al<2, 4, 1, 8, 1><<<g3, 256, 0, stream>>>(aHi, aLo, w3h, w3l, a3s, a3d, h16, als, ald, N);
  aggregate_fused<64, false><<<aggBlocks, 256, 0, stream>>>(h16, als, ald, csrSrc, rowStart, actf, N, b3, 1);

  // ---- MLP head ----
  mlp_kernel<<<(N + 255) / 256, 256, 0, stream>>>(actf, fw1, fb1, fw2, fb2, out, N);
}

// Round 11
// 306.528 us; speedup vs baseline: 1.4621x; 1.1298x over previous
//
#include <hip/hip_runtime.h>
#include <math.h>
#include <stdint.h>

typedef __attribute__((ext_vector_type(8))) short short8v;
typedef __attribute__((ext_vector_type(4))) float float4v;

__device__ __forceinline__ float bf2f(unsigned short u) {
  return __uint_as_float((unsigned int)u << 16);
}
__device__ __forceinline__ unsigned short f2bf(float f) {   // RNE
  unsigned int u = __float_as_uint(f);
  unsigned int r = (u + 0x7FFFu + ((u >> 16) & 1u)) >> 16;
  return (unsigned short)r;
}
__device__ __forceinline__ float exp_lrelu(float x) {
  x = x > 0.f ? x : 0.2f * x;
  return expf(x);       // softmax shift-invariant: segment-max skipped
}

typedef __attribute__((address_space(3))) void lds_void;
typedef const __attribute__((address_space(1))) void glb_void;
__device__ __forceinline__ void gload_lds16(const void* g, void* l) {
  __builtin_amdgcn_global_load_lds((glb_void*)g, (lds_void*)l, 16, 0, 0);
}

// ---------------- weight prep: fp32 W[K][Nw] -> bf16 (RNE) in MFMA-frag order ----
__global__ void wprep_kernel(const float* __restrict__ W, unsigned short* __restrict__ Wh,
                             int K, int Nw)
{
  int t = blockIdx.x * 256 + threadIdx.x;
  if (t >= K * Nw) return;
  int i = t & 7;
  int lane = (t >> 3) & 63;
  int frag = t >> 9;
  int ktiles = K >> 5;
  int n_tile = frag / ktiles, k_tile = frag - n_tile * ktiles;
  int k = k_tile * 32 + ((lane >> 4) << 3) + i;
  int n = (n_tile << 4) + (lane & 15);
  Wh[t] = f2bf(W[(size_t)k * Nw + n]);
}

// ---------------- A-side: x fp32 -> bf16 (RNE) ----------------
__global__ __launch_bounds__(256) void split_kernel(const float* __restrict__ in,
    unsigned short* __restrict__ hi, size_t n4)
{
  size_t i0 = (size_t)blockIdx.x * 256 + threadIdx.x;
  size_t stride = (size_t)gridDim.x * 256;
  for (size_t idx = i0; idx < n4; idx += stride) {
    float4 v = ((const float4*)in)[idx];
    ushort4 h;
    h.x = f2bf(v.x); h.y = f2bf(v.y); h.z = f2bf(v.z); h.w = f2bf(v.w);
    ((ushort4*)hi)[idx] = h;
  }
}

// BN + ELU -> bf16 (RNE), reading bf16 act
__global__ __launch_bounds__(256) void bnsplit_kernel(const unsigned short* __restrict__ act,
    const float* __restrict__ scale, const float* __restrict__ shift,
    unsigned short* __restrict__ hi, size_t nchunks)
{
  size_t i0 = (size_t)blockIdx.x * 256 + threadIdx.x;
  size_t stride = (size_t)gridDim.x * 256;
  for (size_t idx = i0; idx < nchunks; idx += stride) {
    ushort4 u = ((const ushort4*)act)[idx];
    int f = (int)((idx * 4) & 255);
    float4 sc = *(const float4*)(scale + f);
    float4 sh = *(const float4*)(shift + f);
    float v0 = fmaf(bf2f(u.x), sc.x, sh.x);
    float v1 = fmaf(bf2f(u.y), sc.y, sh.y);
    float v2 = fmaf(bf2f(u.z), sc.z, sh.z);
    float v3 = fmaf(bf2f(u.w), sc.w, sh.w);
    v0 = v0 > 0.f ? v0 : expm1f(v0);
    v1 = v1 > 0.f ? v1 : expm1f(v1);
    v2 = v2 > 0.f ? v2 : expm1f(v2);
    v3 = v3 > 0.f ? v3 : expm1f(v3);
    ushort4 h;
    h.x = f2bf(v0); h.y = f2bf(v1); h.z = f2bf(v2); h.w = f2bf(v3);
    ((ushort4*)hi)[idx] = h;
  }
}

// ---------------- single-bf16 MFMA GEMM + fused al epilogue, LDS-staged A ----------------
// K-step BK=64, double-buffered global_load_lds staging.
// LDS: chunk c (k-octet c of the 64-k step) at [g*8192 + c*1024 + row*16], g=row/64.
template<int MI, int WM, int WN, int KSTEPS, int HEADS>
__global__ __launch_bounds__(256) void gemm_al(
    const unsigned short* __restrict__ Ah, const unsigned short* __restrict__ Bh,
    const float* __restrict__ a_s, const float* __restrict__ a_d,
    unsigned short* __restrict__ C, float* __restrict__ al_s, float* __restrict__ al_d,
    int M)
{
  constexpr int BM = WM * MI * 16;
  constexpr int NG = BM / 64;
  constexpr int TILEB = NG * 8192;       // BM rows x 64 k x 2B
  constexpr int Nw = WN * 64, K = KSTEPS * 64;
  constexpr int KT32 = KSTEPS * 2;
  __shared__ __align__(16) unsigned char smem[2][TILEB];

  const int wid = threadIdx.x >> 6, lane = threadIdx.x & 63;
  const int wm = wid / WN, wn = wid % WN;
  const int m0 = blockIdx.x * BM;
  const int n0 = wn * 64;
  const int ar = lane & 15;
  const int cchunk = lane >> 4;
  const int ntile0 = n0 >> 4;

  float4v acc[MI][4];
#pragma unroll
  for (int mi = 0; mi < MI; ++mi)
#pragma unroll
    for (int ni = 0; ni < 4; ++ni)
      acc[mi][ni] = (float4v){0.f, 0.f, 0.f, 0.f};

  auto stage = [&](int buf, int ks) {
#pragma unroll
    for (int j = wid; j < NG * 8; j += 4) {
      int g = j >> 3, c = j & 7;
      const unsigned short* gp = Ah + (size_t)(m0 + g * 64 + lane) * K + ks * 64 + c * 8;
      gload_lds16(gp, &smem[buf][g * 8192 + c * 1024 + lane * 16]);
    }
  };

  stage(0, 0);
  int cur = 0;
  for (int ks = 0; ks < KSTEPS; ++ks) {
    __syncthreads();   // stage(cur) complete; buffers handed off
    // B fragments for the two 32-k tiles of this step (L2-hot, issued before next stage)
    short8v bh[2][4];
#pragma unroll
    for (int hh = 0; hh < 2; ++hh)
#pragma unroll
      for (int ni = 0; ni < 4; ++ni) {
        int kt = ks * 2 + hh;
        size_t off = (((size_t)(ntile0 + ni) * KT32 + kt) * 64 + lane) * 8;
        bh[hh][ni] = *(const short8v*)(Bh + off);
      }
    if (ks + 1 < KSTEPS) stage(cur ^ 1, ks + 1);
    // A fragments from LDS
    short8v ah[2][MI];
#pragma unroll
    for (int hh = 0; hh < 2; ++hh)
#pragma unroll
      for (int mi = 0; mi < MI; ++mi) {
        int row = wm * MI * 16 + mi * 16 + ar;
        int c = hh * 4 + cchunk;
        int off = (row >> 6) * 8192 + c * 1024 + (row & 63) * 16;
        ah[hh][mi] = *(const short8v*)&smem[cur][off];
      }
#pragma unroll
    for (int hh = 0; hh < 2; ++hh)
#pragma unroll
      for (int mi = 0; mi < MI; ++mi)
#pragma unroll
        for (int ni = 0; ni < 4; ++ni)
          acc[mi][ni] = __builtin_amdgcn_mfma_f32_16x16x32_bf16(ah[hh][mi], bh[hh][ni], acc[mi][ni], 0, 0, 0);
    cur ^= 1;
  }

  const int cc = lane & 15;
#pragma unroll
  for (int mi = 0; mi < MI; ++mi) {
    int rowb = m0 + wm * MI * 16 + mi * 16 + ((lane >> 4) << 2);
#pragma unroll
    for (int r = 0; r < 4; ++r) {
      int row = rowb + r;
      if (row < M) {
#pragma unroll
        for (int ni = 0; ni < 4; ++ni)
          C[(size_t)row * Nw + n0 + ni * 16 + cc] = f2bf(acc[mi][ni][r]);
      }
    }
  }

  // fused attention-logit epilogue (bf16-rounded h = downstream values)
  const int head = (HEADS == 4) ? wn : 0;
  float as_[4], ad_[4];
#pragma unroll
  for (int ni = 0; ni < 4; ++ni) {
    as_[ni] = a_s[head * 64 + ni * 16 + cc];
    ad_[ni] = a_d[head * 64 + ni * 16 + cc];
  }
#pragma unroll
  for (int mi = 0; mi < MI; ++mi) {
#pragma unroll
    for (int r = 0; r < 4; ++r) {
      float h0 = bf2f(f2bf(acc[mi][0][r]));
      float h1 = bf2f(f2bf(acc[mi][1][r]));
      float h2 = bf2f(f2bf(acc[mi][2][r]));
      float h3 = bf2f(f2bf(acc[mi][3][r]));
      float ps = h0 * as_[0] + h1 * as_[1] + h2 * as_[2] + h3 * as_[3];
      float pd = h0 * ad_[0] + h1 * ad_[1] + h2 * ad_[2] + h3 * ad_[3];
#pragma unroll
      for (int off = 1; off < 16; off <<= 1) {
        ps += __shfl_xor(ps, off);
        pd += __shfl_xor(pd, off);
      }
      int row = m0 + wm * MI * 16 + mi * 16 + ((lane >> 4) << 2) + r;
      if (cc == 0 && row < M) {
        al_s[row * HEADS + head] = ps;
        al_d[row * HEADS + head] = pd;
      }
    }
  }
}

// ---------------- CSR build ----------------
__global__ void count_kernel(const int* __restrict__ dst, int E, int Etot, int* __restrict__ counts)
{
  int e = blockIdx.x * 256 + threadIdx.x;
  if (e >= Etot) return;
  int d = (e < E) ? dst[e] : (e - E);
  atomicAdd(&counts[d], 1);
}

__global__ void block_sum_kernel(const int* __restrict__ counts, int N, int* __restrict__ bsums)
{
  __shared__ int sd[256];
  int i = blockIdx.x * 256 + threadIdx.x;
  sd[threadIdx.x] = (i < N) ? counts[i] : 0;
  __syncthreads();
  for (int off = 128; off; off >>= 1) {
    if (threadIdx.x < off) sd[threadIdx.x] += sd[threadIdx.x + off];
    __syncthreads();
  }
  if (threadIdx.x == 0) bsums[blockIdx.x] = sd[0];
}

__global__ void scan_bsums_kernel(int* bsums, int nb)
{
  __shared__ int sd[256];
  int t = threadIdx.x;
  int v = (t < nb) ? bsums[t] : 0;
  sd[t] = v;
  __syncthreads();
  for (int off = 1; off < 256; off <<= 1) {
    int x = (t >= off) ? sd[t - off] : 0;
    __syncthreads();
    sd[t] += x;
    __syncthreads();
  }
  if (t < nb) bsums[t] = sd[t] - v;  // exclusive
}

__global__ void scan_write_kernel(const int* __restrict__ counts, int N,
                                  const int* __restrict__ bsums, int* __restrict__ rowStart, int Etot)
{
  __shared__ int sd[256];
  int i = blockIdx.x * 256 + threadIdx.x;
  int v = (i < N) ? counts[i] : 0;
  sd[threadIdx.x] = v;
  __syncthreads();
  for (int off = 1; off < 256; off <<= 1) {
    int x = (threadIdx.x >= off) ? sd[threadIdx.x - off] : 0;
    __syncthreads();
    sd[threadIdx.x] += x;
    __syncthreads();
  }
  if (i < N) rowStart[i] = bsums[blockIdx.x] + sd[threadIdx.x] - v;  // exclusive
  if (i == N - 1) rowStart[N] = Etot;
}

__global__ void fill_kernel(const int* __restrict__ src, const int* __restrict__ dst,
                            int E, int Etot, const int* __restrict__ rowStart,
                            int* __restrict__ cursor, int* __restrict__ csrSrc)
{
  int e = blockIdx.x * 256 + threadIdx.x;
  if (e >= Etot) return;
  int s, d;
  if (e < E) { s = src[e]; d = dst[e]; } else { s = d = e - E; }
  int pos = rowStart[d] + atomicAdd(&cursor[d], 1);
  csrSrc[pos] = s;
}

// ---------------- fused aggregation (edge weights inline); OUT16 -> bf16 output ----
template<int HC_, bool OUT16>
__global__ __launch_bounds__(256) void aggregate_fused(
    const unsigned short* __restrict__ h16,
    const float* __restrict__ als, const float* __restrict__ ald,
    const int* __restrict__ csrSrc, const int* __restrict__ rowStart,
    void* __restrict__ outp, int N, const float* __restrict__ bias, int doElu)
{
  constexpr int H_ = HC_ / 64;
  constexpr int FPL = HC_ / 64;
  __shared__ float ldsW[4][64 * H_];
  const int wl = threadIdx.x >> 6;
  int wid = blockIdx.x * 4 + wl;
  if (wid >= N) return;
  const int lane = threadIdx.x & 63;
  const int head = (H_ == 4) ? (lane >> 4) : 0;
  const int start = rowStart[wid], end = rowStart[wid + 1];

  float ad0, ad1, ad2, ad3;
  if (H_ == 4) {
    float4 adv = ((const float4*)ald)[wid];
    ad0 = adv.x; ad1 = adv.y; ad2 = adv.z; ad3 = adv.w;
  } else {
    ad0 = ald[wid]; ad1 = ad2 = ad3 = 0.f;
  }

  float acc[FPL] = {};
  float wsum = 0.f;

  for (int base = start; base < end; base += 64) {
    int cnt = end - base; if (cnt > 64) cnt = 64;
    int s_l = 0;
    if (lane < cnt) {
      s_l = csrSrc[base + lane];
      if (H_ == 4) {
        float4 av = ((const float4*)als)[s_l];
        float4 w4;
        w4.x = exp_lrelu(av.x + ad0);
        w4.y = exp_lrelu(av.y + ad1);
        w4.z = exp_lrelu(av.z + ad2);
        w4.w = exp_lrelu(av.w + ad3);
        *(float4*)&ldsW[wl][lane * 4] = w4;
      } else {
        ldsW[wl][lane] = exp_lrelu(als[s_l] + ad0);
      }
    }
    int i = 0;
    for (; i + 4 <= cnt; i += 4) {
      int s0 = __shfl(s_l, i);
      int s1 = __shfl(s_l, i + 1);
      int s2 = __shfl(s_l, i + 2);
      int s3 = __shfl(s_l, i + 3);
      float w0 = ldsW[wl][(i + 0) * H_ + head];
      float w1 = ldsW[wl][(i + 1) * H_ + head];
      float w2 = ldsW[wl][(i + 2) * H_ + head];
      float w3 = ldsW[wl][(i + 3) * H_ + head];
      if (FPL == 4) {
        ushort4 r0 = ((const ushort4*)(h16 + (size_t)s0 * HC_))[lane];
        ushort4 r1 = ((const ushort4*)(h16 + (size_t)s1 * HC_))[lane];
        ushort4 r2 = ((const ushort4*)(h16 + (size_t)s2 * HC_))[lane];
        ushort4 r3 = ((const ushort4*)(h16 + (size_t)s3 * HC_))[lane];
        wsum += (w0 + w1) + (w2 + w3);
        acc[0] = fmaf(w0, bf2f(r0.x), acc[0]);
        acc[1] = fmaf(w0, bf2f(r0.y), acc[1]);
        acc[2] = fmaf(w0, bf2f(r0.z), acc[2]);
        acc[3] = fmaf(w0, bf2f(r0.w), acc[3]);
        acc[0] = fmaf(w1, bf2f(r1.x), acc[0]);
        acc[1] = fmaf(w1, bf2f(r1.y), acc[1]);
        acc[2] = fmaf(w1, bf2f(r1.z), acc[2]);
        acc[3] = fmaf(w1, bf2f(r1.w), acc[3]);
        acc[0] = fmaf(w2, bf2f(r2.x), acc[0]);
        acc[1] = fmaf(w2, bf2f(r2.y), acc[1]);
        acc[2] = fmaf(w2, bf2f(r2.z), acc[2]);
        acc[3] = fmaf(w2, bf2f(r2.w), acc[3]);
        acc[0] = fmaf(w3, bf2f(r3.x), acc[0]);
        acc[1] = fmaf(w3, bf2f(r3.y), acc[1]);
        acc[2] = fmaf(w3, bf2f(r3.z), acc[2]);
        acc[3] = fmaf(w3, bf2f(r3.w), acc[3]);
      } else {
        unsigned short r0 = h16[(size_t)s0 * HC_ + lane];
        unsigned short r1 = h16[(size_t)s1 * HC_ + lane];
        unsigned short r2 = h16[(size_t)s2 * HC_ + lane];
        unsigned short r3 = h16[(size_t)s3 * HC_ + lane];
        wsum += (w0 + w1) + (w2 + w3);
        acc[0] = fmaf(w0, bf2f(r0), acc[0]);
        acc[0] = fmaf(w1, bf2f(r1), acc[0]);
        acc[0] = fmaf(w2, bf2f(r2), acc[0]);
        acc[0] = fmaf(w3, bf2f(r3), acc[0]);
      }
    }
    for (; i < cnt; ++i) {
      int s0 = __shfl(s_l, i);
      float w0 = ldsW[wl][i * H_ + head];
      wsum += w0;
      if (FPL == 4) {
        ushort4 r0 = ((const ushort4*)(h16 + (size_t)s0 * HC_))[lane];
        acc[0] = fmaf(w0, bf2f(r0.x), acc[0]);
        acc[1] = fmaf(w0, bf2f(r0.y), acc[1]);
        acc[2] = fmaf(w0, bf2f(r0.z), acc[2]);
        acc[3] = fmaf(w0, bf2f(r0.w), acc[3]);
      } else {
        unsigned short r0 = h16[(size_t)s0 * HC_ + lane];
        acc[0] = fmaf(w0, bf2f(r0), acc[0]);
      }
    }
  }

  float inv = 1.0f / wsum;
  if (FPL == 4) {
    float o0 = acc[0] * inv, o1 = acc[1] * inv, o2 = acc[2] * inv, o3 = acc[3] * inv;
    if (bias) {
      const float4 b = ((const float4*)bias)[lane];
      o0 += b.x; o1 += b.y; o2 += b.z; o3 += b.w;
    }
    if (doElu) {
      o0 = o0 > 0.f ? o0 : expm1f(o0);
      o1 = o1 > 0.f ? o1 : expm1f(o1);
      o2 = o2 > 0.f ? o2 : expm1f(o2);
      o3 = o3 > 0.f ? o3 : expm1f(o3);
    }
    if (OUT16) {
      ushort4 o;
      o.x = f2bf(o0); o.y = f2bf(o1); o.z = f2bf(o2); o.w = f2bf(o3);
      ((ushort4*)((unsigned short*)outp + (size_t)wid * HC_))[lane] = o;
    } else {
      ((float4*)((float*)outp + (size_t)wid * HC_))[lane] = make_float4(o0, o1, o2, o3);
    }
  } else {
    float o = acc[0] * inv;
    if (bias) o += bias[lane];
    if (doElu) o = o > 0.f ? o : expm1f(o);
    if (OUT16) ((unsigned short*)outp)[(size_t)wid * HC_ + lane] = f2bf(o);
    else       ((float*)outp)[(size_t)wid * HC_ + lane] = o;
  }
}

// ---------------- batch norm stats (deterministic partials, no memset/atomics) ----
__global__ __launch_bounds__(256) void bn_stats_kernel(const unsigned short* __restrict__ x, int N,
                                float* __restrict__ partials)   // [128][512]
{
  const int wid = threadIdx.x >> 6, lane = threadIdx.x & 63;
  const int gw = blockIdx.x * 4 + wid;
  const int tw = gridDim.x * 4;
  float4 s = make_float4(0.f, 0.f, 0.f, 0.f);
  float4 q = make_float4(0.f, 0.f, 0.f, 0.f);
#pragma unroll 4
  for (int r = gw; r < N; r += tw) {
    ushort4 u = ((const ushort4*)(x + (size_t)r * 256))[lane];
    float v0 = bf2f(u.x), v1 = bf2f(u.y), v2 = bf2f(u.z), v3 = bf2f(u.w);
    s.x += v0; s.y += v1; s.z += v2; s.w += v3;
    q.x = fmaf(v0, v0, q.x); q.y = fmaf(v1, v1, q.y);
    q.z = fmaf(v2, v2, q.z); q.w = fmaf(v3, v3, q.w);
  }
  __shared__ float ls[4][512];
  *(float4*)&ls[wid][lane * 4] = s;
  *(float4*)&ls[wid][256 + lane * 4] = q;
  __syncthreads();
  const int t = threadIdx.x;
  float a = ls[0][t] + ls[1][t] + ls[2][t] + ls[3][t];
  float b = ls[0][t + 256] + ls[1][t + 256] + ls[2][t + 256] + ls[3][t + 256];
  partials[blockIdx.x * 512 + t] = a;
  partials[blockIdx.x * 512 + 256 + t] = b;
}

__global__ void bn_final_kernel(const float* __restrict__ partials, int nblk,
                                const float* __restrict__ g, const float* __restrict__ be,
                                int N, float* __restrict__ scale, float* __restrict__ shift)
{
  int f = threadIdx.x;
  float s = 0.f, q = 0.f;
#pragma unroll 8
  for (int b = 0; b < nblk; ++b) {
    s += partials[b * 512 + f];
    q += partials[b * 512 + 256 + f];
  }
  float mu = s / N;
  float var = q / N - mu * mu;
  float rs = rsqrtf(var + 1e-5f);
  float sc = g[f] * rs;
  scale[f] = sc;
  shift[f] = be[f] - mu * sc;
}

// ---------------- MLP head: thread-per-node, LDS weight broadcast ----------------
__global__ __launch_bounds__(256) void mlp_kernel(const float* __restrict__ h,
                           const float* __restrict__ fw1,
                           const float* __restrict__ fb1, const float* __restrict__ fw2,
                           const float* __restrict__ fb2, float* __restrict__ out, int N)
{
  __shared__ float w1s[64][32];
  __shared__ float w2s[32][2];
  __shared__ float b1s[32];
  const int t = threadIdx.x;
  for (int i = t; i < 64 * 32; i += 256) w1s[i >> 5][i & 31] = fw1[i];
  if (t < 64) w2s[t >> 1][t & 1] = fw2[t];
  if (t < 32) b1s[t] = fb1[t];
  __syncthreads();

  int n = blockIdx.x * 256 + t;
  if (n >= N) return;

  float hv[64];
#pragma unroll
  for (int k4 = 0; k4 < 16; ++k4) {
    float4 v = *(const float4*)(h + (size_t)n * 64 + k4 * 4);
    hv[k4 * 4 + 0] = v.x; hv[k4 * 4 + 1] = v.y;
    hv[k4 * 4 + 2] = v.z; hv[k4 * 4 + 3] = v.w;
  }
  float hid[32];
#pragma unroll
  for (int j = 0; j < 32; ++j) hid[j] = b1s[j];
#pragma unroll
  for (int k = 0; k < 64; ++k) {
    float hk = hv[k];
#pragma unroll
    for (int jb = 0; jb < 8; ++jb) {
      float4 wv = *(const float4*)&w1s[k][jb * 4];
      hid[jb * 4 + 0] = fmaf(hk, wv.x, hid[jb * 4 + 0]);
      hid[jb * 4 + 1] = fmaf(hk, wv.y, hid[jb * 4 + 1]);
      hid[jb * 4 + 2] = fmaf(hk, wv.z, hid[jb * 4 + 2]);
      hid[jb * 4 + 3] = fmaf(hk, wv.w, hid[jb * 4 + 3]);
    }
  }
  float p0 = fb2[0], p1 = fb2[1];
#pragma unroll
  for (int j = 0; j < 32; ++j) {
    float r = fmaxf(hid[j], 0.f);
    p0 = fmaf(r, w2s[j][0], p0);
    p1 = fmaf(r, w2s[j][1], p1);
  }
  *(float2*)(out + (size_t)n * 2) = make_float2(p0, p1);
}

// ---------------- host ----------------
extern "C" void kernel_launch(void* const* d_in, const int* in_sizes, int n_in,
                              void* d_out, int out_size, void* d_ws, size_t ws_size,
                              hipStream_t stream)
{
  const float* x   = (const float*)d_in[0];
  const int*   ei  = (const int*)d_in[1];
  const float* W1  = (const float*)d_in[2];
  const float* a1s = (const float*)d_in[3];
  const float* a1d = (const float*)d_in[4];
  const float* W2  = (const float*)d_in[6];
  const float* a2s = (const float*)d_in[7];
  const float* a2d = (const float*)d_in[8];
  const float* W3  = (const float*)d_in[10];
  const float* a3s = (const float*)d_in[11];
  const float* a3d = (const float*)d_in[12];
  const float* b3  = (const float*)d_in[13];
  const float* g1  = (const float*)d_in[14];
  const float* be1 = (const float*)d_in[15];
  const float* g2  = (const float*)d_in[16];
  const float* be2 = (const float*)d_in[17];
  const float* fw1 = (const float*)d_in[18];
  const float* fb1 = (const float*)d_in[19];
  const float* fw2 = (const float*)d_in[20];
  const float* fb2 = (const float*)d_in[21];
  float* out = (float*)d_out;

  const int F = 128;
  const int N = in_sizes[0] / F;
  const int E = in_sizes[1] / 2;
  const int Etot = E + N;
  const int* srcIdx = ei;
  const int* dstIdx = ei + E;

  char* w = (char*)d_ws;
  auto alloc = [&](size_t bytes) -> void* {
    void* p = (void*)w;
    w += (bytes + 255) & ~(size_t)255;
    return p;
  };
  unsigned short* h16  = (unsigned short*)alloc((size_t)N * 256 * 2);
  unsigned short* act16= (unsigned short*)alloc((size_t)N * 256 * 2);
  float* actf    = (float*)alloc((size_t)N * 64 * 4);
  unsigned short* aBf  = (unsigned short*)alloc((size_t)N * 256 * 2);
  float* als     = (float*)alloc((size_t)N * 4 * 4);
  float* ald     = (float*)alloc((size_t)N * 4 * 4);
  int*   counts  = (int*)alloc((size_t)N * 4);
  int*   cursor  = (int*)alloc((size_t)N * 4);
  int*   rowStart= (int*)alloc((size_t)(N + 1) * 4);
  int*   csrSrc  = (int*)alloc((size_t)Etot * 4);
  int*   bsums   = (int*)alloc((size_t)((N + 255) / 256) * 4);
  float* partials= (float*)alloc((size_t)128 * 512 * 4);
  float* scale1  = (float*)alloc(256 * 4);
  float* shift1  = (float*)alloc(256 * 4);
  float* scale2  = (float*)alloc(256 * 4);
  float* shift2  = (float*)alloc(256 * 4);
  unsigned short* w1h = (unsigned short*)alloc((size_t)128 * 256 * 2);
  unsigned short* w2h = (unsigned short*)alloc((size_t)256 * 256 * 2);
  unsigned short* w3h = (unsigned short*)alloc((size_t)256 * 64 * 2);
  // slack so OOB staging reads of the last GEMM block stay in-bounds
  (void)alloc(65536);

  const int nb = (N + 255) / 256;
  const int ebk = (Etot + 255) / 256;
  const int aggBlocks = (N + 3) / 4;

  // ---- weight prep ----
  wprep_kernel<<<(128 * 256 + 255) / 256, 256, 0, stream>>>(W1, w1h, 128, 256);
  wprep_kernel<<<(256 * 256 + 255) / 256, 256, 0, stream>>>(W2, w2h, 256, 256);
  wprep_kernel<<<(256 * 64 + 255) / 256, 256, 0, stream>>>(W3, w3h, 256, 64);

  // ---- CSR build ----
  hipMemsetAsync(counts, 0, (size_t)N * 4, stream);
  hipMemsetAsync(cursor, 0, (size_t)N * 4, stream);
  count_kernel<<<ebk, 256, 0, stream>>>(dstIdx, E, Etot, counts);
  block_sum_kernel<<<nb, 256, 0, stream>>>(counts, N, bsums);
  scan_bsums_kernel<<<1, 256, 0, stream>>>(bsums, nb);
  scan_write_kernel<<<nb, 256, 0, stream>>>(counts, N, bsums, rowStart, Etot);
  fill_kernel<<<ebk, 256, 0, stream>>>(srcIdx, dstIdx, E, Etot, rowStart, cursor, csrSrc);

  dim3 g12((N + 63) / 64, 1);      // layers 1,2: MI=4, WM=1, WN=4 (BM=64, BN=256)
  dim3 g3((N + 127) / 128, 1);     // layer 3:   MI=2, WM=4, WN=1 (BM=128, BN=64)

  // ---- GAT layer 1 ----
  split_kernel<<<2048, 256, 0, stream>>>(x, aBf, (size_t)N * 128 / 4);
  gemm_al<4, 1, 4, 2, 4><<<g12, 256, 0, stream>>>(aBf, w1h, a1s, a1d, h16, als, ald, N);
  aggregate_fused<256, true><<<aggBlocks, 256, 0, stream>>>(h16, als, ald, csrSrc, rowStart, act16, N, nullptr, 0);
  bn_stats_kernel<<<128, 256, 0, stream>>>(act16, N, partials);
  bn_final_kernel<<<1, 256, 0, stream>>>(partials, 128, g1, be1, N, scale1, shift1);

  // ---- GAT layer 2 ----
  bnsplit_kernel<<<2048, 256, 0, stream>>>(act16, scale1, shift1, aBf, (size_t)N * 64);
  gemm_al<4, 1, 4, 4, 4><<<g12, 256, 0, stream>>>(aBf, w2h, a2s, a2d, h16, als, ald, N);
  aggregate_fused<256, true><<<aggBlocks, 256, 0, stream>>>(h16, als, ald, csrSrc, rowStart, act16, N, nullptr, 0);
  bn_stats_kernel<<<128, 256, 0, stream>>>(act16, N, partials);
  bn_final_kernel<<<1, 256, 0, stream>>>(partials, 128, g2, be2, N, scale2, shift2);

  // ---- GAT layer 3 ----
  bnsplit_kernel<<<2048, 256, 0, stream>>>(act16, scale2, shift2, aBf, (size_t)N * 64);
  gemm_al<2, 4, 1, 4, 1><<<g3, 256, 0, stream>>>(aBf, w3h, a3s, a3d, h16, als, ald, N);
  aggregate_fused<64, false><<<aggBlocks, 256, 0, stream>>>(h16, als, ald, csrSrc, rowStart, actf, N, b3, 1);

  // ---- MLP head ----
  mlp_kernel<<<(N + 255) / 256, 256, 0, stream>>>(actf, fw1, fb1, fw2, fb2, out, N);
}

// Round 12
// 306.121 us; speedup vs baseline: 1.4640x; 1.0013x over previous
//
#include <hip/hip_runtime.h>
#include <math.h>
#include <stdint.h>

typedef __attribute__((ext_vector_type(8))) short short8v;
typedef __attribute__((ext_vector_type(4))) float float4v;

__device__ __forceinline__ float bf2f(unsigned short u) {
  return __uint_as_float((unsigned int)u << 16);
}
__device__ __forceinline__ unsigned short f2bf(float f) {   // RNE
  unsigned int u = __float_as_uint(f);
  unsigned int r = (u + 0x7FFFu + ((u >> 16) & 1u)) >> 16;
  return (unsigned short)r;
}
__device__ __forceinline__ float exp_lrelu(float x) {
  x = x > 0.f ? x : 0.2f * x;
  return expf(x);       // softmax shift-invariant: segment-max skipped
}

typedef __attribute__((address_space(3))) void lds_void;
typedef const __attribute__((address_space(1))) void glb_void;
__device__ __forceinline__ void gload_lds16(const void* g, void* l) {
  __builtin_amdgcn_global_load_lds((glb_void*)g, (lds_void*)l, 16, 0, 0);
}

// ---------------- weight prep (all 3 weights in one dispatch) ----------------
// fp32 W[K][Nw] -> bf16 (RNE) in MFMA-frag order.
__device__ __forceinline__ void wprep_one(const float* W, unsigned short* Wh,
                                          int t, int K, int Nw)
{
  int i = t & 7;
  int lane = (t >> 3) & 63;
  int frag = t >> 9;
  int ktiles = K >> 5;
  int n_tile = frag / ktiles, k_tile = frag - n_tile * ktiles;
  int k = k_tile * 32 + ((lane >> 4) << 3) + i;
  int n = (n_tile << 4) + (lane & 15);
  Wh[t] = f2bf(W[(size_t)k * Nw + n]);
}

__global__ void wprep_all_kernel(const float* __restrict__ W1, unsigned short* __restrict__ w1h,
                                 const float* __restrict__ W2, unsigned short* __restrict__ w2h,
                                 const float* __restrict__ W3, unsigned short* __restrict__ w3h)
{
  int t = blockIdx.x * 256 + threadIdx.x;
  const int s1 = 128 * 256, s2 = 256 * 256, s3 = 256 * 64;
  if (t < s1) { wprep_one(W1, w1h, t, 128, 256); return; }
  t -= s1;
  if (t < s2) { wprep_one(W2, w2h, t, 256, 256); return; }
  t -= s2;
  if (t < s3) { wprep_one(W3, w3h, t, 256, 64); }
}

// ---------------- A-side: x fp32 -> bf16 (RNE) ----------------
__global__ __launch_bounds__(256) void split_kernel(const float* __restrict__ in,
    unsigned short* __restrict__ hi, size_t n4)
{
  size_t i0 = (size_t)blockIdx.x * 256 + threadIdx.x;
  size_t stride = (size_t)gridDim.x * 256;
  for (size_t idx = i0; idx < n4; idx += stride) {
    float4 v = ((const float4*)in)[idx];
    ushort4 h;
    h.x = f2bf(v.x); h.y = f2bf(v.y); h.z = f2bf(v.z); h.w = f2bf(v.w);
    ((ushort4*)hi)[idx] = h;
  }
}

// BN + ELU -> bf16 (RNE), reading bf16 act
__global__ __launch_bounds__(256) void bnsplit_kernel(const unsigned short* __restrict__ act,
    const float* __restrict__ scale, const float* __restrict__ shift,
    unsigned short* __restrict__ hi, size_t nchunks)
{
  size_t i0 = (size_t)blockIdx.x * 256 + threadIdx.x;
  size_t stride = (size_t)gridDim.x * 256;
  for (size_t idx = i0; idx < nchunks; idx += stride) {
    ushort4 u = ((const ushort4*)act)[idx];
    int f = (int)((idx * 4) & 255);
    float4 sc = *(const float4*)(scale + f);
    float4 sh = *(const float4*)(shift + f);
    float v0 = fmaf(bf2f(u.x), sc.x, sh.x);
    float v1 = fmaf(bf2f(u.y), sc.y, sh.y);
    float v2 = fmaf(bf2f(u.z), sc.z, sh.z);
    float v3 = fmaf(bf2f(u.w), sc.w, sh.w);
    v0 = v0 > 0.f ? v0 : expm1f(v0);
    v1 = v1 > 0.f ? v1 : expm1f(v1);
    v2 = v2 > 0.f ? v2 : expm1f(v2);
    v3 = v3 > 0.f ? v3 : expm1f(v3);
    ushort4 h;
    h.x = f2bf(v0); h.y = f2bf(v1); h.z = f2bf(v2); h.w = f2bf(v3);
    ((ushort4*)hi)[idx] = h;
  }
}

// ---------------- single-bf16 MFMA GEMM + fused al epilogue, LDS-staged A ----------------
// 128-thread blocks (2 waves): more independent pipelines per CU than 4-wave blocks.
// K-step BK=64, double-buffered global_load_lds staging. grid.y splits N.
// LDS: chunk c (k-octet c of the 64-k step) at [c*1024 + row*16] (BM=64 rows).
template<int MI, int WM, int WN, int KSTEPS, int HEADS>
__global__ __launch_bounds__(128) void gemm_al(
    const unsigned short* __restrict__ Ah, const unsigned short* __restrict__ Bh,
    const float* __restrict__ a_s, const float* __restrict__ a_d,
    unsigned short* __restrict__ C, float* __restrict__ al_s, float* __restrict__ al_d,
    int M)
{
  constexpr int NWAVES = WM * WN;            // 2
  constexpr int BM = WM * MI * 16;           // 64
  constexpr int TILEB = BM * 64 * 2;         // 8 KB per buffer
  constexpr int Nw = HEADS * 64;             // 256 (4-head) or 64 (1-head)
  constexpr int K = KSTEPS * 64;
  constexpr int KT32 = KSTEPS * 2;
  __shared__ __align__(16) unsigned char smem[2][TILEB];

  const int wid = threadIdx.x >> 6, lane = threadIdx.x & 63;
  const int wm = wid / WN, wn = wid % WN;
  const int gn = blockIdx.y * WN + wn;       // global 64-col tile index
  const int m0 = blockIdx.x * BM;
  const int n0 = gn * 64;
  const int ar = lane & 15;
  const int cchunk = lane >> 4;
  const int ntile0 = n0 >> 4;

  float4v acc[MI][4];
#pragma unroll
  for (int mi = 0; mi < MI; ++mi)
#pragma unroll
    for (int ni = 0; ni < 4; ++ni)
      acc[mi][ni] = (float4v){0.f, 0.f, 0.f, 0.f};

  auto stage = [&](int buf, int ks) {
#pragma unroll
    for (int c = wid; c < 8; c += NWAVES) {
      const unsigned short* gp = Ah + (size_t)(m0 + lane) * K + ks * 64 + c * 8;
      gload_lds16(gp, &smem[buf][c * 1024 + lane * 16]);
    }
  };

  stage(0, 0);
  int cur = 0;
  for (int ks = 0; ks < KSTEPS; ++ks) {
    __syncthreads();   // stage(cur) complete; buffers handed off
    // B fragments for the two 32-k tiles of this step (L2-hot)
    short8v bh[2][4];
#pragma unroll
    for (int hh = 0; hh < 2; ++hh)
#pragma unroll
      for (int ni = 0; ni < 4; ++ni) {
        int kt = ks * 2 + hh;
        size_t off = (((size_t)(ntile0 + ni) * KT32 + kt) * 64 + lane) * 8;
        bh[hh][ni] = *(const short8v*)(Bh + off);
      }
    if (ks + 1 < KSTEPS) stage(cur ^ 1, ks + 1);
    // A fragments from LDS
    short8v ah[2][MI];
#pragma unroll
    for (int hh = 0; hh < 2; ++hh)
#pragma unroll
      for (int mi = 0; mi < MI; ++mi) {
        int row = wm * MI * 16 + mi * 16 + ar;
        int c = hh * 4 + cchunk;
        int off = c * 1024 + row * 16;
        ah[hh][mi] = *(const short8v*)&smem[cur][off];
      }
#pragma unroll
    for (int hh = 0; hh < 2; ++hh)
#pragma unroll
      for (int mi = 0; mi < MI; ++mi)
#pragma unroll
        for (int ni = 0; ni < 4; ++ni)
          acc[mi][ni] = __builtin_amdgcn_mfma_f32_16x16x32_bf16(ah[hh][mi], bh[hh][ni], acc[mi][ni], 0, 0, 0);
    cur ^= 1;
  }

  const int cc = lane & 15;
#pragma unroll
  for (int mi = 0; mi < MI; ++mi) {
    int rowb = m0 + wm * MI * 16 + mi * 16 + ((lane >> 4) << 2);
#pragma unroll
    for (int r = 0; r < 4; ++r) {
      int row = rowb + r;
      if (row < M) {
#pragma unroll
        for (int ni = 0; ni < 4; ++ni)
          C[(size_t)row * Nw + n0 + ni * 16 + cc] = f2bf(acc[mi][ni][r]);
      }
    }
  }

  // fused attention-logit epilogue (bf16-rounded h = downstream values)
  const int head = (HEADS == 4) ? gn : 0;
  float as_[4], ad_[4];
#pragma unroll
  for (int ni = 0; ni < 4; ++ni) {
    as_[ni] = a_s[head * 64 + ni * 16 + cc];
    ad_[ni] = a_d[head * 64 + ni * 16 + cc];
  }
#pragma unroll
  for (int mi = 0; mi < MI; ++mi) {
#pragma unroll
    for (int r = 0; r < 4; ++r) {
      float h0 = bf2f(f2bf(acc[mi][0][r]));
      float h1 = bf2f(f2bf(acc[mi][1][r]));
      float h2 = bf2f(f2bf(acc[mi][2][r]));
      float h3 = bf2f(f2bf(acc[mi][3][r]));
      float ps = h0 * as_[0] + h1 * as_[1] + h2 * as_[2] + h3 * as_[3];
      float pd = h0 * ad_[0] + h1 * ad_[1] + h2 * ad_[2] + h3 * ad_[3];
#pragma unroll
      for (int off = 1; off < 16; off <<= 1) {
        ps += __shfl_xor(ps, off);
        pd += __shfl_xor(pd, off);
      }
      int row = m0 + wm * MI * 16 + mi * 16 + ((lane >> 4) << 2) + r;
      if (cc == 0 && row < M) {
        al_s[row * HEADS + head] = ps;
        al_d[row * HEADS + head] = pd;
      }
    }
  }
}

// ---------------- CSR build ----------------
__global__ void count_kernel(const int* __restrict__ dst, int E, int Etot, int* __restrict__ counts)
{
  int e = blockIdx.x * 256 + threadIdx.x;
  if (e >= Etot) return;
  int d = (e < E) ? dst[e] : (e - E);
  atomicAdd(&counts[d], 1);
}

__global__ void block_sum_kernel(const int* __restrict__ counts, int N, int* __restrict__ bsums)
{
  __shared__ int sd[256];
  int i = blockIdx.x * 256 + threadIdx.x;
  sd[threadIdx.x] = (i < N) ? counts[i] : 0;
  __syncthreads();
  for (int off = 128; off; off >>= 1) {
    if (threadIdx.x < off) sd[threadIdx.x] += sd[threadIdx.x + off];
    __syncthreads();
  }
  if (threadIdx.x == 0) bsums[blockIdx.x] = sd[0];
}

__global__ void scan_bsums_kernel(int* bsums, int nb)
{
  __shared__ int sd[256];
  int t = threadIdx.x;
  int v = (t < nb) ? bsums[t] : 0;
  sd[t] = v;
  __syncthreads();
  for (int off = 1; off < 256; off <<= 1) {
    int x = (t >= off) ? sd[t - off] : 0;
    __syncthreads();
    sd[t] += x;
    __syncthreads();
  }
  if (t < nb) bsums[t] = sd[t] - v;  // exclusive
}

__global__ void scan_write_kernel(const int* __restrict__ counts, int N,
                                  const int* __restrict__ bsums, int* __restrict__ rowStart, int Etot)
{
  __shared__ int sd[256];
  int i = blockIdx.x * 256 + threadIdx.x;
  int v = (i < N) ? counts[i] : 0;
  sd[threadIdx.x] = v;
  __syncthreads();
  for (int off = 1; off < 256; off <<= 1) {
    int x = (threadIdx.x >= off) ? sd[threadIdx.x - off] : 0;
    __syncthreads();
    sd[threadIdx.x] += x;
    __syncthreads();
  }
  if (i < N) rowStart[i] = bsums[blockIdx.x] + sd[threadIdx.x] - v;  // exclusive
  if (i == N - 1) rowStart[N] = Etot;
}

__global__ void fill_kernel(const int* __restrict__ src, const int* __restrict__ dst,
                            int E, int Etot, const int* __restrict__ rowStart,
                            int* __restrict__ cursor, int* __restrict__ csrSrc)
{
  int e = blockIdx.x * 256 + threadIdx.x;
  if (e >= Etot) return;
  int s, d;
  if (e < E) { s = src[e]; d = dst[e]; } else { s = d = e - E; }
  int pos = rowStart[d] + atomicAdd(&cursor[d], 1);
  csrSrc[pos] = s;
}

// ---------------- fused aggregation (edge weights inline); OUT16 -> bf16 output ----
template<int HC_, bool OUT16>
__global__ __launch_bounds__(256) void aggregate_fused(
    const unsigned short* __restrict__ h16,
    const float* __restrict__ als, const float* __restrict__ ald,
    const int* __restrict__ csrSrc, const int* __restrict__ rowStart,
    void* __restrict__ outp, int N, const float* __restrict__ bias, int doElu)
{
  constexpr int H_ = HC_ / 64;
  constexpr int FPL = HC_ / 64;
  __shared__ float ldsW[4][64 * H_];
  const int wl = threadIdx.x >> 6;
  int wid = blockIdx.x * 4 + wl;
  if (wid >= N) return;
  const int lane = threadIdx.x & 63;
  const int head = (H_ == 4) ? (lane >> 4) : 0;
  const int start = rowStart[wid], end = rowStart[wid + 1];

  float ad0, ad1, ad2, ad3;
  if (H_ == 4) {
    float4 adv = ((const float4*)ald)[wid];
    ad0 = adv.x; ad1 = adv.y; ad2 = adv.z; ad3 = adv.w;
  } else {
    ad0 = ald[wid]; ad1 = ad2 = ad3 = 0.f;
  }

  float acc[FPL] = {};
  float wsum = 0.f;

  for (int base = start; base < end; base += 64) {
    int cnt = end - base; if (cnt > 64) cnt = 64;
    int s_l = 0;
    if (lane < cnt) {
      s_l = csrSrc[base + lane];
      if (H_ == 4) {
        float4 av = ((const float4*)als)[s_l];
        float4 w4;
        w4.x = exp_lrelu(av.x + ad0);
        w4.y = exp_lrelu(av.y + ad1);
        w4.z = exp_lrelu(av.z + ad2);
        w4.w = exp_lrelu(av.w + ad3);
        *(float4*)&ldsW[wl][lane * 4] = w4;
      } else {
        ldsW[wl][lane] = exp_lrelu(als[s_l] + ad0);
      }
    }
    int i = 0;
    for (; i + 4 <= cnt; i += 4) {
      int s0 = __shfl(s_l, i);
      int s1 = __shfl(s_l, i + 1);
      int s2 = __shfl(s_l, i + 2);
      int s3 = __shfl(s_l, i + 3);
      float w0 = ldsW[wl][(i + 0) * H_ + head];
      float w1 = ldsW[wl][(i + 1) * H_ + head];
      float w2 = ldsW[wl][(i + 2) * H_ + head];
      float w3 = ldsW[wl][(i + 3) * H_ + head];
      if (FPL == 4) {
        ushort4 r0 = ((const ushort4*)(h16 + (size_t)s0 * HC_))[lane];
        ushort4 r1 = ((const ushort4*)(h16 + (size_t)s1 * HC_))[lane];
        ushort4 r2 = ((const ushort4*)(h16 + (size_t)s2 * HC_))[lane];
        ushort4 r3 = ((const ushort4*)(h16 + (size_t)s3 * HC_))[lane];
        wsum += (w0 + w1) + (w2 + w3);
        acc[0] = fmaf(w0, bf2f(r0.x), acc[0]);
        acc[1] = fmaf(w0, bf2f(r0.y), acc[1]);
        acc[2] = fmaf(w0, bf2f(r0.z), acc[2]);
        acc[3] = fmaf(w0, bf2f(r0.w), acc[3]);
        acc[0] = fmaf(w1, bf2f(r1.x), acc[0]);
        acc[1] = fmaf(w1, bf2f(r1.y), acc[1]);
        acc[2] = fmaf(w1, bf2f(r1.z), acc[2]);
        acc[3] = fmaf(w1, bf2f(r1.w), acc[3]);
        acc[0] = fmaf(w2, bf2f(r2.x), acc[0]);
        acc[1] = fmaf(w2, bf2f(r2.y), acc[1]);
        acc[2] = fmaf(w2, bf2f(r2.z), acc[2]);
        acc[3] = fmaf(w2, bf2f(r2.w), acc[3]);
        acc[0] = fmaf(w3, bf2f(r3.x), acc[0]);
        acc[1] = fmaf(w3, bf2f(r3.y), acc[1]);
        acc[2] = fmaf(w3, bf2f(r3.z), acc[2]);
        acc[3] = fmaf(w3, bf2f(r3.w), acc[3]);
      } else {
        unsigned short r0 = h16[(size_t)s0 * HC_ + lane];
        unsigned short r1 = h16[(size_t)s1 * HC_ + lane];
        unsigned short r2 = h16[(size_t)s2 * HC_ + lane];
        unsigned short r3 = h16[(size_t)s3 * HC_ + lane];
        wsum += (w0 + w1) + (w2 + w3);
        acc[0] = fmaf(w0, bf2f(r0), acc[0]);
        acc[0] = fmaf(w1, bf2f(r1), acc[0]);
        acc[0] = fmaf(w2, bf2f(r2), acc[0]);
        acc[0] = fmaf(w3, bf2f(r3), acc[0]);
      }
    }
    for (; i < cnt; ++i) {
      int s0 = __shfl(s_l, i);
      float w0 = ldsW[wl][i * H_ + head];
      wsum += w0;
      if (FPL == 4) {
        ushort4 r0 = ((const ushort4*)(h16 + (size_t)s0 * HC_))[lane];
        acc[0] = fmaf(w0, bf2f(r0.x), acc[0]);
        acc[1] = fmaf(w0, bf2f(r0.y), acc[1]);
        acc[2] = fmaf(w0, bf2f(r0.z), acc[2]);
        acc[3] = fmaf(w0, bf2f(r0.w), acc[3]);
      } else {
        unsigned short r0 = h16[(size_t)s0 * HC_ + lane];
        acc[0] = fmaf(w0, bf2f(r0), acc[0]);
      }
    }
  }

  float inv = 1.0f / wsum;
  if (FPL == 4) {
    float o0 = acc[0] * inv, o1 = acc[1] * inv, o2 = acc[2] * inv, o3 = acc[3] * inv;
    if (bias) {
      const float4 b = ((const float4*)bias)[lane];
      o0 += b.x; o1 += b.y; o2 += b.z; o3 += b.w;
    }
    if (doElu) {
      o0 = o0 > 0.f ? o0 : expm1f(o0);
      o1 = o1 > 0.f ? o1 : expm1f(o1);
      o2 = o2 > 0.f ? o2 : expm1f(o2);
      o3 = o3 > 0.f ? o3 : expm1f(o3);
    }
    if (OUT16) {
      ushort4 o;
      o.x = f2bf(o0); o.y = f2bf(o1); o.z = f2bf(o2); o.w = f2bf(o3);
      ((ushort4*)((unsigned short*)outp + (size_t)wid * HC_))[lane] = o;
    } else {
      ((float4*)((float*)outp + (size_t)wid * HC_))[lane] = make_float4(o0, o1, o2, o3);
    }
  } else {
    float o = acc[0] * inv;
    if (bias) o += bias[lane];
    if (doElu) o = o > 0.f ? o : expm1f(o);
    if (OUT16) ((unsigned short*)outp)[(size_t)wid * HC_ + lane] = f2bf(o);
    else       ((float*)outp)[(size_t)wid * HC_ + lane] = o;
  }
}

// ---------------- batch norm stats (deterministic partials, no memset/atomics) ----
__global__ __launch_bounds__(256) void bn_stats_kernel(const unsigned short* __restrict__ x, int N,
                                float* __restrict__ partials)   // [128][512]
{
  const int wid = threadIdx.x >> 6, lane = threadIdx.x & 63;
  const int gw = blockIdx.x * 4 + wid;
  const int tw = gridDim.x * 4;
  float4 s = make_float4(0.f, 0.f, 0.f, 0.f);
  float4 q = make_float4(0.f, 0.f, 0.f, 0.f);
#pragma unroll 4
  for (int r = gw; r < N; r += tw) {
    ushort4 u = ((const ushort4*)(x + (size_t)r * 256))[lane];
    float v0 = bf2f(u.x), v1 = bf2f(u.y), v2 = bf2f(u.z), v3 = bf2f(u.w);
    s.x += v0; s.y += v1; s.z += v2; s.w += v3;
    q.x = fmaf(v0, v0, q.x); q.y = fmaf(v1, v1, q.y);
    q.z = fmaf(v2, v2, q.z); q.w = fmaf(v3, v3, q.w);
  }
  __shared__ float ls[4][512];
  *(float4*)&ls[wid][lane * 4] = s;
  *(float4*)&ls[wid][256 + lane * 4] = q;
  __syncthreads();
  const int t = threadIdx.x;
  float a = ls[0][t] + ls[1][t] + ls[2][t] + ls[3][t];
  float b = ls[0][t + 256] + ls[1][t + 256] + ls[2][t + 256] + ls[3][t + 256];
  partials[blockIdx.x * 512 + t] = a;
  partials[blockIdx.x * 512 + 256 + t] = b;
}

__global__ void bn_final_kernel(const float* __restrict__ partials, int nblk,
                                const float* __restrict__ g, const float* __restrict__ be,
                                int N, float* __restrict__ scale, float* __restrict__ shift)
{
  int f = threadIdx.x;
  float s = 0.f, q = 0.f;
#pragma unroll 8
  for (int b = 0; b < nblk; ++b) {
    s += partials[b * 512 + f];
    q += partials[b * 512 + 256 + f];
  }
  float mu = s / N;
  float var = q / N - mu * mu;
  float rs = rsqrtf(var + 1e-5f);
  float sc = g[f] * rs;
  scale[f] = sc;
  shift[f] = be[f] - mu * sc;
}

// ---------------- MLP head: thread-per-node, LDS weight broadcast ----------------
__global__ __launch_bounds__(256) void mlp_kernel(const float* __restrict__ h,
                           const float* __restrict__ fw1,
                           const float* __restrict__ fb1, const float* __restrict__ fw2,
                           const float* __restrict__ fb2, float* __restrict__ out, int N)
{
  __shared__ float w1s[64][32];
  __shared__ float w2s[32][2];
  __shared__ float b1s[32];
  const int t = threadIdx.x;
  for (int i = t; i < 64 * 32; i += 256) w1s[i >> 5][i & 31] = fw1[i];
  if (t < 64) w2s[t >> 1][t & 1] = fw2[t];
  if (t < 32) b1s[t] = fb1[t];
  __syncthreads();

  int n = blockIdx.x * 256 + t;
  if (n >= N) return;

  float hv[64];
#pragma unroll
  for (int k4 = 0; k4 < 16; ++k4) {
    float4 v = *(const float4*)(h + (size_t)n * 64 + k4 * 4);
    hv[k4 * 4 + 0] = v.x; hv[k4 * 4 + 1] = v.y;
    hv[k4 * 4 + 2] = v.z; hv[k4 * 4 + 3] = v.w;
  }
  float hid[32];
#pragma unroll
  for (int j = 0; j < 32; ++j) hid[j] = b1s[j];
#pragma unroll
  for (int k = 0; k < 64; ++k) {
    float hk = hv[k];
#pragma unroll
    for (int jb = 0; jb < 8; ++jb) {
      float4 wv = *(const float4*)&w1s[k][jb * 4];
      hid[jb * 4 + 0] = fmaf(hk, wv.x, hid[jb * 4 + 0]);
      hid[jb * 4 + 1] = fmaf(hk, wv.y, hid[jb * 4 + 1]);
      hid[jb * 4 + 2] = fmaf(hk, wv.z, hid[jb * 4 + 2]);
      hid[jb * 4 + 3] = fmaf(hk, wv.w, hid[jb * 4 + 3]);
    }
  }
  float p0 = fb2[0], p1 = fb2[1];
#pragma unroll
  for (int j = 0; j < 32; ++j) {
    float r = fmaxf(hid[j], 0.f);
    p0 = fmaf(r, w2s[j][0], p0);
    p1 = fmaf(r, w2s[j][1], p1);
  }
  *(float2*)(out + (size_t)n * 2) = make_float2(p0, p1);
}

// ---------------- host ----------------
extern "C" void kernel_launch(void* const* d_in, const int* in_sizes, int n_in,
                              void* d_out, int out_size, void* d_ws, size_t ws_size,
                              hipStream_t stream)
{
  const float* x   = (const float*)d_in[0];
  const int*   ei  = (const int*)d_in[1];
  const float* W1  = (const float*)d_in[2];
  const float* a1s = (const float*)d_in[3];
  const float* a1d = (const float*)d_in[4];
  const float* W2  = (const float*)d_in[6];
  const float* a2s = (const float*)d_in[7];
  const float* a2d = (const float*)d_in[8];
  const float* W3  = (const float*)d_in[10];
  const float* a3s = (const float*)d_in[11];
  const float* a3d = (const float*)d_in[12];
  const float* b3  = (const float*)d_in[13];
  const float* g1  = (const float*)d_in[14];
  const float* be1 = (const float*)d_in[15];
  const float* g2  = (const float*)d_in[16];
  const float* be2 = (const float*)d_in[17];
  const float* fw1 = (const float*)d_in[18];
  const float* fb1 = (const float*)d_in[19];
  const float* fw2 = (const float*)d_in[20];
  const float* fb2 = (const float*)d_in[21];
  float* out = (float*)d_out;

  const int F = 128;
  const int N = in_sizes[0] / F;
  const int E = in_sizes[1] / 2;
  const int Etot = E + N;
  const int* srcIdx = ei;
  const int* dstIdx = ei + E;

  char* w = (char*)d_ws;
  auto alloc = [&](size_t bytes) -> void* {
    void* p = (void*)w;
    w += (bytes + 255) & ~(size_t)255;
    return p;
  };
  unsigned short* h16  = (unsigned short*)alloc((size_t)N * 256 * 2);
  unsigned short* act16= (unsigned short*)alloc((size_t)N * 256 * 2);
  float* actf    = (float*)alloc((size_t)N * 64 * 4);
  unsigned short* aBf  = (unsigned short*)alloc((size_t)N * 256 * 2);
  float* als     = (float*)alloc((size_t)N * 4 * 4);
  float* ald     = (float*)alloc((size_t)N * 4 * 4);
  const size_t cntPad = ((size_t)N * 4 + 255) & ~(size_t)255;
  int*   counts  = (int*)alloc((size_t)N * 4);
  int*   cursor  = (int*)alloc((size_t)N * 4);     // contiguous after counts (cntPad apart)
  int*   rowStart= (int*)alloc((size_t)(N + 1) * 4);
  int*   csrSrc  = (int*)alloc((size_t)Etot * 4);
  int*   bsums   = (int*)alloc((size_t)((N + 255) / 256) * 4);
  float* partials= (float*)alloc((size_t)128 * 512 * 4);
  float* scale1  = (float*)alloc(256 * 4);
  float* shift1  = (float*)alloc(256 * 4);
  float* scale2  = (float*)alloc(256 * 4);
  float* shift2  = (float*)alloc(256 * 4);
  unsigned short* w1h = (unsigned short*)alloc((size_t)128 * 256 * 2);
  unsigned short* w2h = (unsigned short*)alloc((size_t)256 * 256 * 2);
  unsigned short* w3h = (unsigned short*)alloc((size_t)256 * 64 * 2);
  // slack so OOB staging reads of the last GEMM block stay in-bounds
  (void)alloc(65536);

  const int nb = (N + 255) / 256;
  const int ebk = (Etot + 255) / 256;
  const int aggBlocks = (N + 3) / 4;

  // ---- weight prep (one dispatch for all three) ----
  const int wtot = 128 * 256 + 256 * 256 + 256 * 64;
  wprep_all_kernel<<<(wtot + 255) / 256, 256, 0, stream>>>(W1, w1h, W2, w2h, W3, w3h);

  // ---- CSR build ----
  hipMemsetAsync(counts, 0, cntPad + (size_t)N * 4, stream);   // counts + cursor in one memset
  count_kernel<<<ebk, 256, 0, stream>>>(dstIdx, E, Etot, counts);
  block_sum_kernel<<<nb, 256, 0, stream>>>(counts, N, bsums);
  scan_bsums_kernel<<<1, 256, 0, stream>>>(bsums, nb);
  scan_write_kernel<<<nb, 256, 0, stream>>>(counts, N, bsums, rowStart, Etot);
  fill_kernel<<<ebk, 256, 0, stream>>>(srcIdx, dstIdx, E, Etot, rowStart, cursor, csrSrc);

  dim3 g12((N + 63) / 64, 2);      // layers 1,2: MI=4,WM=1,WN=2 -> BM=64,BN=128, 128 thr
  dim3 g3((N + 63) / 64, 1);       // layer 3:   MI=2,WM=2,WN=1 -> BM=64,BN=64, 128 thr

  // ---- GAT layer 1 ----
  split_kernel<<<2048, 256, 0, stream>>>(x, aBf, (size_t)N * 128 / 4);
  gemm_al<4, 1, 2, 2, 4><<<g12, 128, 0, stream>>>(aBf, w1h, a1s, a1d, h16, als, ald, N);
  aggregate_fused<256, true><<<aggBlocks, 256, 0, stream>>>(h16, als, ald, csrSrc, rowStart, act16, N, nullptr, 0);
  bn_stats_kernel<<<128, 256, 0, stream>>>(act16, N, partials);
  bn_final_kernel<<<1, 256, 0, stream>>>(partials, 128, g1, be1, N, scale1, shift1);

  // ---- GAT layer 2 ----
  bnsplit_kernel<<<2048, 256, 0, stream>>>(act16, scale1, shift1, aBf, (size_t)N * 64);
  gemm_al<4, 1, 2, 4, 4><<<g12, 128, 0, stream>>>(aBf, w2h, a2s, a2d, h16, als, ald, N);
  aggregate_fused<256, true><<<aggBlocks, 256, 0, stream>>>(h16, als, ald, csrSrc, rowStart, act16, N, nullptr, 0);
  bn_stats_kernel<<<128, 256, 0, stream>>>(act16, N, partials);
  bn_final_kernel<<<1, 256, 0, stream>>>(partials, 128, g2, be2, N, scale2, shift2);

  // ---- GAT layer 3 ----
  bnsplit_kernel<<<2048, 256, 0, stream>>>(act16, scale2, shift2, aBf, (size_t)N * 64);
  gemm_al<2, 2, 1, 4, 1><<<g3, 128, 0, stream>>>(aBf, w3h, a3s, a3d, h16, als, ald, N);
  aggregate_fused<64, false><<<aggBlocks, 256, 0, stream>>>(h16, als, ald, csrSrc, rowStart, actf, N, b3, 1);

  // ---- MLP head ----
  mlp_kernel<<<(N + 255) / 256, 256, 0, stream>>>(actf, fw1, fb1, fw2, fb2, out, N);
}